// Round 1
// baseline (2028.375 us; speedup 1.0000x reference)
//
#include <hip/hip_runtime.h>
#include <hip/hip_bf16.h>

// ResidualGATBlock: LN1 -> GATv2(4 heads) -> gelu -> +time_cond +x -> LN2 -> FFN -> residual
// N=100000, E=1600000, D=128, H=4, HD=32, B=8, TD=128. All f32 I/O.

#define D128 128
#define RB 16
#define NEG_SLOPE 0.2f
#define LN_EPS 1e-5f

__device__ __forceinline__ float gelu_erf(float v) {
    return 0.5f * v * (1.0f + erff(v * 0.70710678118654752f));
}

// ---------------------------------------------------------------------------
// Kernel 1: LN1 fused with dual GEMM  (feat_src = LN(x)@Wsrc+bsrc, feat_dst = ...)
// block: 256 threads, 16 rows. LDS: staged+normalized rows.
// ---------------------------------------------------------------------------
__global__ __launch_bounds__(256) void ln1_dual_gemm(
    const float* __restrict__ x,
    const float* __restrict__ ln_g, const float* __restrict__ ln_b,
    const float* __restrict__ Wsrc, const float* __restrict__ bsrc,
    const float* __restrict__ Wdst, const float* __restrict__ bdst,
    float* __restrict__ fs, float* __restrict__ fd, int nrows)
{
    __shared__ __align__(16) float hs[RB][D128];
    __shared__ float s_mu[RB], s_rs[RB];

    const int tid  = threadIdx.x;
    const int row0 = blockIdx.x * RB;

    // ---- load 16 rows (2048 floats) as float4, 8 floats/thread ----
    {
        const float4* xv = (const float4*)(x + (size_t)row0 * D128);
        float4* hv = (float4*)&hs[0][0];
        #pragma unroll
        for (int i = 0; i < 2; ++i) {
            int f   = tid + i * 256;       // float4 index within tile
            int row = f >> 5;              // 32 float4 per row
            float4 v = make_float4(0.f, 0.f, 0.f, 0.f);
            if (row0 + row < nrows) v = xv[f];
            hv[f] = v;
        }
    }
    __syncthreads();

    // ---- per-row mean / rstd (wave per row, 4 rows per wave) ----
    {
        const int wv = tid >> 6, ln = tid & 63;
        #pragma unroll
        for (int rr = 0; rr < 4; ++rr) {
            int row = wv * 4 + rr;
            float v0 = hs[row][ln * 2], v1 = hs[row][ln * 2 + 1];
            float s = v0 + v1, sq = v0 * v0 + v1 * v1;
            #pragma unroll
            for (int m = 32; m; m >>= 1) { s += __shfl_xor(s, m); sq += __shfl_xor(sq, m); }
            if (ln == 0) {
                float mu  = s * (1.0f / 128.0f);
                float var = sq * (1.0f / 128.0f) - mu * mu;
                s_mu[row] = mu;
                s_rs[row] = rsqrtf(var + LN_EPS);
            }
        }
    }
    __syncthreads();

    // ---- normalize in place ----
    #pragma unroll
    for (int i = 0; i < 2; ++i) {
        int f   = tid + i * 256;
        int row = f >> 5;
        int c0  = (f & 31) * 4;
        float mu = s_mu[row], rs = s_rs[row];
        float4 g4 = *(const float4*)&ln_g[c0];
        float4 b4 = *(const float4*)&ln_b[c0];
        float4 v  = *(float4*)&hs[row][c0];
        v.x = (v.x - mu) * rs * g4.x + b4.x;
        v.y = (v.y - mu) * rs * g4.y + b4.y;
        v.z = (v.z - mu) * rs * g4.z + b4.z;
        v.w = (v.w - mu) * rs * g4.w + b4.w;
        *(float4*)&hs[row][c0] = v;
    }
    __syncthreads();

    // ---- dual GEMM: col c = tid&127, row group rg = tid>>7 (8 rows each) ----
    const int c  = tid & 127;
    const int rg = tid >> 7;
    float accS[8], accD[8];
    #pragma unroll
    for (int r = 0; r < 8; ++r) { accS[r] = 0.f; accD[r] = 0.f; }

    for (int kk = 0; kk < 128; kk += 4) {
        float ws0 = Wsrc[(kk + 0) * 128 + c];
        float ws1 = Wsrc[(kk + 1) * 128 + c];
        float ws2 = Wsrc[(kk + 2) * 128 + c];
        float ws3 = Wsrc[(kk + 3) * 128 + c];
        float wd0 = Wdst[(kk + 0) * 128 + c];
        float wd1 = Wdst[(kk + 1) * 128 + c];
        float wd2 = Wdst[(kk + 2) * 128 + c];
        float wd3 = Wdst[(kk + 3) * 128 + c];
        #pragma unroll
        for (int r = 0; r < 8; ++r) {
            float4 a = *(const float4*)&hs[rg * 8 + r][kk];
            accS[r] = fmaf(a.x, ws0, accS[r]);
            accS[r] = fmaf(a.y, ws1, accS[r]);
            accS[r] = fmaf(a.z, ws2, accS[r]);
            accS[r] = fmaf(a.w, ws3, accS[r]);
            accD[r] = fmaf(a.x, wd0, accD[r]);
            accD[r] = fmaf(a.y, wd1, accD[r]);
            accD[r] = fmaf(a.z, wd2, accD[r]);
            accD[r] = fmaf(a.w, wd3, accD[r]);
        }
    }

    const float bs = bsrc[c], bd = bdst[c];
    #pragma unroll
    for (int r = 0; r < 8; ++r) {
        int row = row0 + rg * 8 + r;
        if (row < nrows) {
            fs[(size_t)row * 128 + c] = accS[r] + bs;
            fd[(size_t)row * 128 + c] = accD[r] + bd;
        }
    }
}

// ---------------------------------------------------------------------------
// Kernel 2: time MLP  time_cond = gelu(time_emb @ tW + tb)   (B x 128, tiny)
// ---------------------------------------------------------------------------
__global__ __launch_bounds__(256) void time_mlp(
    const float* __restrict__ temb, const float* __restrict__ tW,
    const float* __restrict__ tb, float* __restrict__ tc, int B)
{
    __shared__ float te[8 * 128];
    int tid = threadIdx.x;
    for (int i = tid; i < B * 128; i += 256) te[i] = temb[i];
    __syncthreads();
    int c = tid & 127, half = tid >> 7;
    for (int b = half * 4; b < half * 4 + 4; ++b) {
        if (b >= B) break;
        float acc = 0.f;
        for (int k = 0; k < 128; ++k) acc = fmaf(te[b * 128 + k], tW[k * 128 + c], acc);
        tc[b * 128 + c] = gelu_erf(acc + tb[c]);
    }
}

// ---------------------------------------------------------------------------
// Kernel 3: per-edge scores -> ex = exp(score), denom[dst][h] += ex (atomic)
// one wave per edge (grid-stride). lane l handles dims 2l, 2l+1.
// ---------------------------------------------------------------------------
__global__ __launch_bounds__(256) void edge_scores(
    const float* __restrict__ fs, const float* __restrict__ fd,
    const int* __restrict__ src, const int* __restrict__ dst,
    const float* __restrict__ attn,
    float* __restrict__ ex, float* __restrict__ denom, int E)
{
    const int lane = threadIdx.x & 63;
    const int wib  = threadIdx.x >> 6;
    const int wave = blockIdx.x * (blockDim.x >> 6) + wib;
    const int nwv  = gridDim.x * (blockDim.x >> 6);

    const int head = lane >> 4;
    const int hd0  = (lane & 15) * 2;
    const float a0 = attn[head * 32 + hd0];
    const float a1 = attn[head * 32 + hd0 + 1];

    for (int e = wave; e < E; e += nwv) {
        int s = src[e], d = dst[e];
        float2 vs = *(const float2*)(fs + (size_t)s * 128 + lane * 2);
        float2 vd = *(const float2*)(fd + (size_t)d * 128 + lane * 2);
        float e0 = vs.x + vd.x; e0 = e0 > 0.f ? e0 : NEG_SLOPE * e0;
        float e1 = vs.y + vd.y; e1 = e1 > 0.f ? e1 : NEG_SLOPE * e1;
        float p = e0 * a0 + e1 * a1;
        p += __shfl_xor(p, 8);
        p += __shfl_xor(p, 4);
        p += __shfl_xor(p, 2);
        p += __shfl_xor(p, 1);
        if ((lane & 15) == 0) {
            float exv = expf(p);
            ex[(size_t)e * 4 + head] = exv;
            atomicAdd(denom + (size_t)d * 4 + head, exv);
        }
    }
}

// ---------------------------------------------------------------------------
// Kernel 4: scatter messages  rst[dst] += alpha * feat_src[src]   (atomics)
// ---------------------------------------------------------------------------
__global__ __launch_bounds__(256) void edge_scatter(
    const float* __restrict__ fs,
    const int* __restrict__ src, const int* __restrict__ dst,
    const float* __restrict__ ex, const float* __restrict__ denom,
    float* __restrict__ rst, int E)
{
    const int lane = threadIdx.x & 63;
    const int wib  = threadIdx.x >> 6;
    const int wave = blockIdx.x * (blockDim.x >> 6) + wib;
    const int nwv  = gridDim.x * (blockDim.x >> 6);
    const int head = lane >> 4;

    for (int e = wave; e < E; e += nwv) {
        int s = src[e], d = dst[e];
        float alpha = ex[(size_t)e * 4 + head] / denom[(size_t)d * 4 + head];
        float2 vs = *(const float2*)(fs + (size_t)s * 128 + lane * 2);
        atomicAdd(rst + (size_t)d * 128 + lane * 2,     vs.x * alpha);
        atomicAdd(rst + (size_t)d * 128 + lane * 2 + 1, vs.y * alpha);
    }
}

// ---------------------------------------------------------------------------
// Kernel 5: combine + LN2 + FFN, fully fused per 16-row tile.
//   hmid = gelu(rst + gat_bias) + time_cond[gid] + x
//   out  = hmid + gelu(LN2(hmid) @ W1 + b1) @ W2 + b2
// ---------------------------------------------------------------------------
__global__ __launch_bounds__(256) void combine_ffn(
    const float* __restrict__ rst, const float* __restrict__ x,
    const int* __restrict__ gid, const float* __restrict__ tc,
    const float* __restrict__ gat_bias,
    const float* __restrict__ ln_g, const float* __restrict__ ln_b,
    const float* __restrict__ W1, const float* __restrict__ b1,
    const float* __restrict__ W2, const float* __restrict__ b2,
    float* __restrict__ out, int nrows)
{
    __shared__ __align__(16) float hm[RB][D128];   // hmid (residual source)
    __shared__ __align__(16) float lnv[RB][D128];  // LN2(hmid)
    __shared__ __align__(16) float tt[RB][256];    // gelu(ln @ W1 + b1)
    __shared__ float s_mu[RB], s_rs[RB];

    const int tid  = threadIdx.x;
    const int row0 = blockIdx.x * RB;

    // ---- build hmid ----
    #pragma unroll
    for (int i = 0; i < 2; ++i) {
        int f   = tid + i * 256;
        int row = f >> 5;
        int c0  = (f & 31) * 4;
        int gr  = row0 + row;
        float4 v = make_float4(0.f, 0.f, 0.f, 0.f);
        if (gr < nrows) {
            float4 r4 = *(const float4*)(rst + (size_t)gr * 128 + c0);
            float4 x4 = *(const float4*)(x   + (size_t)gr * 128 + c0);
            float4 gb = *(const float4*)&gat_bias[c0];
            int g = gid[gr];
            float4 t4 = *(const float4*)(tc + (size_t)g * 128 + c0);
            v.x = gelu_erf(r4.x + gb.x) + t4.x + x4.x;
            v.y = gelu_erf(r4.y + gb.y) + t4.y + x4.y;
            v.z = gelu_erf(r4.z + gb.z) + t4.z + x4.z;
            v.w = gelu_erf(r4.w + gb.w) + t4.w + x4.w;
        }
        *(float4*)&hm[row][c0] = v;
    }
    __syncthreads();

    // ---- LN2: wave per row ----
    {
        const int wv = tid >> 6, ln = tid & 63;
        #pragma unroll
        for (int rr = 0; rr < 4; ++rr) {
            int row = wv * 4 + rr;
            float v0 = hm[row][ln * 2], v1 = hm[row][ln * 2 + 1];
            float s = v0 + v1, sq = v0 * v0 + v1 * v1;
            #pragma unroll
            for (int m = 32; m; m >>= 1) { s += __shfl_xor(s, m); sq += __shfl_xor(sq, m); }
            if (ln == 0) {
                float mu  = s * (1.0f / 128.0f);
                float var = sq * (1.0f / 128.0f) - mu * mu;
                s_mu[row] = mu;
                s_rs[row] = rsqrtf(var + LN_EPS);
            }
        }
    }
    __syncthreads();
    #pragma unroll
    for (int i = 0; i < 2; ++i) {
        int f   = tid + i * 256;
        int row = f >> 5;
        int c0  = (f & 31) * 4;
        float mu = s_mu[row], rs = s_rs[row];
        float4 g4 = *(const float4*)&ln_g[c0];
        float4 b4 = *(const float4*)&ln_b[c0];
        float4 v  = *(float4*)&hm[row][c0];
        v.x = (v.x - mu) * rs * g4.x + b4.x;
        v.y = (v.y - mu) * rs * g4.y + b4.y;
        v.z = (v.z - mu) * rs * g4.z + b4.z;
        v.w = (v.w - mu) * rs * g4.w + b4.w;
        *(float4*)&lnv[row][c0] = v;
    }
    __syncthreads();

    // ---- GEMM1: [16x128] @ [128x256] -> gelu -> tt ----
    {
        const int c = tid;                       // 0..255
        float acc[16];
        #pragma unroll
        for (int r = 0; r < 16; ++r) acc[r] = 0.f;
        for (int kk = 0; kk < 128; kk += 4) {
            float w0 = W1[(kk + 0) * 256 + c];
            float w1 = W1[(kk + 1) * 256 + c];
            float w2 = W1[(kk + 2) * 256 + c];
            float w3 = W1[(kk + 3) * 256 + c];
            #pragma unroll
            for (int r = 0; r < 16; ++r) {
                float4 a = *(const float4*)&lnv[r][kk];
                acc[r] = fmaf(a.x, w0, acc[r]);
                acc[r] = fmaf(a.y, w1, acc[r]);
                acc[r] = fmaf(a.z, w2, acc[r]);
                acc[r] = fmaf(a.w, w3, acc[r]);
            }
        }
        float bb = b1[c];
        #pragma unroll
        for (int r = 0; r < 16; ++r) tt[r][c] = gelu_erf(acc[r] + bb);
    }
    __syncthreads();

    // ---- GEMM2: [16x256] @ [256x128] + hmid + b2 -> out ----
    {
        const int c  = tid & 127;
        const int rg = tid >> 7;
        float acc[8];
        #pragma unroll
        for (int r = 0; r < 8; ++r) acc[r] = 0.f;
        for (int kk = 0; kk < 256; kk += 4) {
            float w0 = W2[(kk + 0) * 128 + c];
            float w1 = W2[(kk + 1) * 128 + c];
            float w2 = W2[(kk + 2) * 128 + c];
            float w3 = W2[(kk + 3) * 128 + c];
            #pragma unroll
            for (int r = 0; r < 8; ++r) {
                float4 a = *(const float4*)&tt[rg * 8 + r][kk];
                acc[r] = fmaf(a.x, w0, acc[r]);
                acc[r] = fmaf(a.y, w1, acc[r]);
                acc[r] = fmaf(a.z, w2, acc[r]);
                acc[r] = fmaf(a.w, w3, acc[r]);
            }
        }
        float bb = b2[c];
        #pragma unroll
        for (int r = 0; r < 8; ++r) {
            int row = row0 + rg * 8 + r;
            if (row < nrows)
                out[(size_t)row * 128 + c] = hm[rg * 8 + r][c] + acc[r] + bb;
        }
    }
}

// ---------------------------------------------------------------------------
extern "C" void kernel_launch(void* const* d_in, const int* in_sizes, int n_in,
                              void* d_out, int out_size, void* d_ws, size_t ws_size,
                              hipStream_t stream)
{
    const float* x    = (const float*)d_in[0];
    const int*   src  = (const int*)  d_in[1];
    const int*   dst  = (const int*)  d_in[2];
    const int*   gid  = (const int*)  d_in[3];
    const float* temb = (const float*)d_in[4];
    const float* Wsrc = (const float*)d_in[5];
    const float* bsrc = (const float*)d_in[6];
    const float* Wdst = (const float*)d_in[7];
    const float* bdst = (const float*)d_in[8];
    const float* attn = (const float*)d_in[9];
    const float* gbias= (const float*)d_in[10];
    const float* ln1g = (const float*)d_in[11];
    const float* ln1b = (const float*)d_in[12];
    const float* ln2g = (const float*)d_in[13];
    const float* ln2b = (const float*)d_in[14];
    const float* tW   = (const float*)d_in[15];
    const float* tb   = (const float*)d_in[16];
    const float* W1   = (const float*)d_in[17];
    const float* b1   = (const float*)d_in[18];
    const float* W2   = (const float*)d_in[19];
    const float* b2   = (const float*)d_in[20];

    const int N = in_sizes[0] / 128;
    const int E = in_sizes[1];
    const int B = in_sizes[4] / 128;
    float* out = (float*)d_out;

    // workspace layout (bytes):
    //   fs    : N*128*4   = 51.2 MB
    //   fd/rst: N*128*4   = 51.2 MB   (feat_dst, reused as rst after edge_scores)
    //   ex    : E*4*4     = 25.6 MB
    //   denom : N*4*4     =  1.6 MB
    //   tc    : B*128*4
    char* ws = (char*)d_ws;
    size_t off = 0;
    float* fs    = (float*)(ws + off); off += (size_t)N * 128 * 4;
    float* fd    = (float*)(ws + off); off += (size_t)N * 128 * 4;
    float* ex    = (float*)(ws + off); off += (size_t)E * 4 * 4;
    float* denom = (float*)(ws + off); off += (size_t)N * 4 * 4;
    float* tc    = (float*)(ws + off); off += (size_t)B * 128 * 4;

    hipMemsetAsync(denom, 0, (size_t)N * 4 * 4, stream);
    time_mlp<<<1, 256, 0, stream>>>(temb, tW, tb, tc, B);
    ln1_dual_gemm<<<(N + RB - 1) / RB, 256, 0, stream>>>(
        x, ln1g, ln1b, Wsrc, bsrc, Wdst, bdst, fs, fd, N);
    edge_scores<<<4096, 256, 0, stream>>>(fs, fd, src, dst, attn, ex, denom, E);
    hipMemsetAsync(fd, 0, (size_t)N * 128 * 4, stream);   // fd becomes rst
    edge_scatter<<<4096, 256, 0, stream>>>(fs, src, dst, ex, denom, fd, E);
    combine_ffn<<<(N + RB - 1) / RB, 256, 0, stream>>>(
        fd, x, gid, tc, gbias, ln2g, ln2b, W1, b1, W2, b2, out, N);
}

// Round 2
// 955.039 us; speedup vs baseline: 2.1239x; 2.1239x over previous
//
#include <hip/hip_runtime.h>
#include <hip/hip_bf16.h>

// ResidualGATBlock: LN1 -> GATv2(4 heads) -> gelu -> +time_cond +x -> LN2 -> FFN -> residual
// N=100000, E=1600000, D=128, H=4, HD=32, B=8, TD=128. All f32 I/O.
// Round 2: CSR gather replaces atomic scatter; edge stage fully fused per node.

#define D128 128
#define RB 16
#define NEG_SLOPE 0.2f
#define LN_EPS 1e-5f

__device__ __forceinline__ float gelu_erf(float v) {
    return 0.5f * v * (1.0f + erff(v * 0.70710678118654752f));
}

// ---------------------------------------------------------------------------
// Kernel 1: LN1 fused with dual GEMM  (feat_src = LN(x)@Wsrc+bsrc, feat_dst = ...)
// ---------------------------------------------------------------------------
__global__ __launch_bounds__(256) void ln1_dual_gemm(
    const float* __restrict__ x,
    const float* __restrict__ ln_g, const float* __restrict__ ln_b,
    const float* __restrict__ Wsrc, const float* __restrict__ bsrc,
    const float* __restrict__ Wdst, const float* __restrict__ bdst,
    float* __restrict__ fs, float* __restrict__ fd, int nrows)
{
    __shared__ __align__(16) float hs[RB][D128];
    __shared__ float s_mu[RB], s_rs[RB];

    const int tid  = threadIdx.x;
    const int row0 = blockIdx.x * RB;

    {
        const float4* xv = (const float4*)(x + (size_t)row0 * D128);
        float4* hv = (float4*)&hs[0][0];
        #pragma unroll
        for (int i = 0; i < 2; ++i) {
            int f   = tid + i * 256;
            int row = f >> 5;
            float4 v = make_float4(0.f, 0.f, 0.f, 0.f);
            if (row0 + row < nrows) v = xv[f];
            hv[f] = v;
        }
    }
    __syncthreads();

    {
        const int wv = tid >> 6, ln = tid & 63;
        #pragma unroll
        for (int rr = 0; rr < 4; ++rr) {
            int row = wv * 4 + rr;
            float v0 = hs[row][ln * 2], v1 = hs[row][ln * 2 + 1];
            float s = v0 + v1, sq = v0 * v0 + v1 * v1;
            #pragma unroll
            for (int m = 32; m; m >>= 1) { s += __shfl_xor(s, m); sq += __shfl_xor(sq, m); }
            if (ln == 0) {
                float mu  = s * (1.0f / 128.0f);
                float var = sq * (1.0f / 128.0f) - mu * mu;
                s_mu[row] = mu;
                s_rs[row] = rsqrtf(var + LN_EPS);
            }
        }
    }
    __syncthreads();

    #pragma unroll
    for (int i = 0; i < 2; ++i) {
        int f   = tid + i * 256;
        int row = f >> 5;
        int c0  = (f & 31) * 4;
        float mu = s_mu[row], rs = s_rs[row];
        float4 g4 = *(const float4*)&ln_g[c0];
        float4 b4 = *(const float4*)&ln_b[c0];
        float4 v  = *(float4*)&hs[row][c0];
        v.x = (v.x - mu) * rs * g4.x + b4.x;
        v.y = (v.y - mu) * rs * g4.y + b4.y;
        v.z = (v.z - mu) * rs * g4.z + b4.z;
        v.w = (v.w - mu) * rs * g4.w + b4.w;
        *(float4*)&hs[row][c0] = v;
    }
    __syncthreads();

    const int c  = tid & 127;
    const int rg = tid >> 7;
    float accS[8], accD[8];
    #pragma unroll
    for (int r = 0; r < 8; ++r) { accS[r] = 0.f; accD[r] = 0.f; }

    for (int kk = 0; kk < 128; kk += 4) {
        float ws0 = Wsrc[(kk + 0) * 128 + c];
        float ws1 = Wsrc[(kk + 1) * 128 + c];
        float ws2 = Wsrc[(kk + 2) * 128 + c];
        float ws3 = Wsrc[(kk + 3) * 128 + c];
        float wd0 = Wdst[(kk + 0) * 128 + c];
        float wd1 = Wdst[(kk + 1) * 128 + c];
        float wd2 = Wdst[(kk + 2) * 128 + c];
        float wd3 = Wdst[(kk + 3) * 128 + c];
        #pragma unroll
        for (int r = 0; r < 8; ++r) {
            float4 a = *(const float4*)&hs[rg * 8 + r][kk];
            accS[r] = fmaf(a.x, ws0, accS[r]);
            accS[r] = fmaf(a.y, ws1, accS[r]);
            accS[r] = fmaf(a.z, ws2, accS[r]);
            accS[r] = fmaf(a.w, ws3, accS[r]);
            accD[r] = fmaf(a.x, wd0, accD[r]);
            accD[r] = fmaf(a.y, wd1, accD[r]);
            accD[r] = fmaf(a.z, wd2, accD[r]);
            accD[r] = fmaf(a.w, wd3, accD[r]);
        }
    }

    const float bs = bsrc[c], bd = bdst[c];
    #pragma unroll
    for (int r = 0; r < 8; ++r) {
        int row = row0 + rg * 8 + r;
        if (row < nrows) {
            fs[(size_t)row * 128 + c] = accS[r] + bs;
            fd[(size_t)row * 128 + c] = accD[r] + bd;
        }
    }
}

// ---------------------------------------------------------------------------
// Kernel 2: time MLP  time_cond = gelu(time_emb @ tW + tb)
// ---------------------------------------------------------------------------
__global__ __launch_bounds__(256) void time_mlp(
    const float* __restrict__ temb, const float* __restrict__ tW,
    const float* __restrict__ tb, float* __restrict__ tc, int B)
{
    __shared__ float te[8 * 128];
    int tid = threadIdx.x;
    for (int i = tid; i < B * 128; i += 256) te[i] = temb[i];
    __syncthreads();
    int c = tid & 127, half = tid >> 7;
    for (int b = half * 4; b < half * 4 + 4; ++b) {
        if (b >= B) break;
        float acc = 0.f;
        for (int k = 0; k < 128; ++k) acc = fmaf(te[b * 128 + k], tW[k * 128 + c], acc);
        tc[b * 128 + c] = gelu_erf(acc + tb[c]);
    }
}

// ---------------------------------------------------------------------------
// CSR build: rank -> scan -> fill
// ---------------------------------------------------------------------------
__global__ __launch_bounds__(256) void csr_rank(
    const int* __restrict__ dst, int* __restrict__ deg, int* __restrict__ rank, int E)
{
    int e = blockIdx.x * 256 + threadIdx.x;
    if (e < E) rank[e] = atomicAdd(&deg[dst[e]], 1);
}

__global__ __launch_bounds__(1024) void csr_scan(
    const int* __restrict__ deg, int* __restrict__ rs, int N, int E)
{
    __shared__ int wsum[16];
    const int t = threadIdx.x;
    const int C = (N + 1023) >> 10;
    const int lo = t * C;
    const int hi = min(N, lo + C);
    int s = 0;
    for (int i = lo; i < hi; ++i) s += deg[i];
    const int lane = t & 63, w = t >> 6;
    int v = s;
    #pragma unroll
    for (int m = 1; m < 64; m <<= 1) { int u = __shfl_up(v, m); if (lane >= m) v += u; }
    if (lane == 63) wsum[w] = v;
    __syncthreads();
    if (t == 0) {
        int acc = 0;
        for (int i = 0; i < 16; ++i) { int u = wsum[i]; wsum[i] = acc; acc += u; }
    }
    __syncthreads();
    int acc = wsum[w] + (v - s);        // exclusive prefix for this thread's chunk
    for (int i = lo; i < hi; ++i) { rs[i] = acc; acc += deg[i]; }
    if (t == 0) rs[N] = E;
}

__global__ __launch_bounds__(256) void csr_fill(
    const int* __restrict__ dst, const int* __restrict__ rs,
    const int* __restrict__ rank, int* __restrict__ eidx, int E)
{
    int e = blockIdx.x * 256 + threadIdx.x;
    if (e < E) eidx[rs[dst[e]] + rank[e]] = e;
}

// ---------------------------------------------------------------------------
// Kernel 3: fused GAT gather. One wave per node.
//  - fd[n] row held in registers across the node's edge list
//  - per edge: read fs[src] row, leaky_relu, score, 16-lane reduce, exp,
//    accumulate denom + weighted sum in ONE pass
//  - writes hmid = gelu(rst + gat_bias) + time_cond[gid] + x  in place over fd
// ---------------------------------------------------------------------------
__global__ __launch_bounds__(256) void gat_gather(
    const float* __restrict__ fs, float* __restrict__ fd,
    const float* __restrict__ x,
    const int* __restrict__ eidx, const int* __restrict__ rs,
    const int* __restrict__ srcArr,
    const float* __restrict__ attn, const float* __restrict__ gat_bias,
    const int* __restrict__ gid, const float* __restrict__ tc, int N)
{
    const int lane = threadIdx.x & 63;
    const int wib  = threadIdx.x >> 6;
    const int n    = blockIdx.x * 4 + wib;
    if (n >= N) return;

    const int head = lane >> 4;
    const int d0   = lane * 2;
    const float a0 = attn[head * 32 + (lane & 15) * 2];
    const float a1 = attn[head * 32 + (lane & 15) * 2 + 1];

    const float2 vd = *(const float2*)(fd + (size_t)n * 128 + d0);
    const int lo = rs[n], hi = rs[n + 1];

    float den = 0.f, w0 = 0.f, w1 = 0.f;
    for (int i = lo; i < hi; ++i) {
        int e = eidx[i];
        int s = srcArr[e];
        float2 vs = *(const float2*)(fs + (size_t)s * 128 + d0);
        float e0 = vs.x + vd.x; e0 = e0 > 0.f ? e0 : NEG_SLOPE * e0;
        float e1 = vs.y + vd.y; e1 = e1 > 0.f ? e1 : NEG_SLOPE * e1;
        float p = e0 * a0 + e1 * a1;
        p += __shfl_xor(p, 8);
        p += __shfl_xor(p, 4);
        p += __shfl_xor(p, 2);
        p += __shfl_xor(p, 1);
        float exv = __expf(p);
        den += exv;
        w0 = fmaf(exv, vs.x, w0);
        w1 = fmaf(exv, vs.y, w1);
    }
    const float inv = den > 0.f ? 1.0f / den : 0.f;
    const float r0 = w0 * inv, r1 = w1 * inv;

    const int g = gid[n];
    const float2 xx = *(const float2*)(x  + (size_t)n * 128 + d0);
    const float2 t2 = *(const float2*)(tc + (size_t)g * 128 + d0);
    float h0 = gelu_erf(r0 + gat_bias[d0])     + t2.x + xx.x;
    float h1 = gelu_erf(r1 + gat_bias[d0 + 1]) + t2.y + xx.y;
    *(float2*)(fd + (size_t)n * 128 + d0) = make_float2(h0, h1);
}

// ---------------------------------------------------------------------------
// Kernel 4: LN2 + FFN per 16-row tile (hmid comes precomputed).
//   out = hmid + gelu(LN2(hmid) @ W1 + b1) @ W2 + b2
// ---------------------------------------------------------------------------
__global__ __launch_bounds__(256) void combine_ffn(
    const float* __restrict__ hmg,
    const float* __restrict__ ln_g, const float* __restrict__ ln_b,
    const float* __restrict__ W1, const float* __restrict__ b1,
    const float* __restrict__ W2, const float* __restrict__ b2,
    float* __restrict__ out, int nrows)
{
    __shared__ __align__(16) float hm[RB][D128];
    __shared__ __align__(16) float lnv[RB][D128];
    __shared__ __align__(16) float tt[RB][256];
    __shared__ float s_mu[RB], s_rs[RB];

    const int tid  = threadIdx.x;
    const int row0 = blockIdx.x * RB;

    // ---- load hmid tile ----
    {
        const float4* hv = (const float4*)(hmg + (size_t)row0 * D128);
        float4* dv = (float4*)&hm[0][0];
        #pragma unroll
        for (int i = 0; i < 2; ++i) {
            int f   = tid + i * 256;
            int row = f >> 5;
            float4 v = make_float4(0.f, 0.f, 0.f, 0.f);
            if (row0 + row < nrows) v = hv[f];
            dv[f] = v;
        }
    }
    __syncthreads();

    // ---- LN2 ----
    {
        const int wv = tid >> 6, ln = tid & 63;
        #pragma unroll
        for (int rr = 0; rr < 4; ++rr) {
            int row = wv * 4 + rr;
            float v0 = hm[row][ln * 2], v1 = hm[row][ln * 2 + 1];
            float s = v0 + v1, sq = v0 * v0 + v1 * v1;
            #pragma unroll
            for (int m = 32; m; m >>= 1) { s += __shfl_xor(s, m); sq += __shfl_xor(sq, m); }
            if (ln == 0) {
                float mu  = s * (1.0f / 128.0f);
                float var = sq * (1.0f / 128.0f) - mu * mu;
                s_mu[row] = mu;
                s_rs[row] = rsqrtf(var + LN_EPS);
            }
        }
    }
    __syncthreads();
    #pragma unroll
    for (int i = 0; i < 2; ++i) {
        int f   = tid + i * 256;
        int row = f >> 5;
        int c0  = (f & 31) * 4;
        float mu = s_mu[row], rs = s_rs[row];
        float4 g4 = *(const float4*)&ln_g[c0];
        float4 b4 = *(const float4*)&ln_b[c0];
        float4 v  = *(float4*)&hm[row][c0];
        v.x = (v.x - mu) * rs * g4.x + b4.x;
        v.y = (v.y - mu) * rs * g4.y + b4.y;
        v.z = (v.z - mu) * rs * g4.z + b4.z;
        v.w = (v.w - mu) * rs * g4.w + b4.w;
        *(float4*)&lnv[row][c0] = v;
    }
    __syncthreads();

    // ---- GEMM1: [16x128] @ [128x256] -> gelu -> tt ----
    {
        const int c = tid;
        float acc[16];
        #pragma unroll
        for (int r = 0; r < 16; ++r) acc[r] = 0.f;
        for (int kk = 0; kk < 128; kk += 4) {
            float w0 = W1[(kk + 0) * 256 + c];
            float w1 = W1[(kk + 1) * 256 + c];
            float w2 = W1[(kk + 2) * 256 + c];
            float w3 = W1[(kk + 3) * 256 + c];
            #pragma unroll
            for (int r = 0; r < 16; ++r) {
                float4 a = *(const float4*)&lnv[r][kk];
                acc[r] = fmaf(a.x, w0, acc[r]);
                acc[r] = fmaf(a.y, w1, acc[r]);
                acc[r] = fmaf(a.z, w2, acc[r]);
                acc[r] = fmaf(a.w, w3, acc[r]);
            }
        }
        float bb = b1[c];
        #pragma unroll
        for (int r = 0; r < 16; ++r) tt[r][c] = gelu_erf(acc[r] + bb);
    }
    __syncthreads();

    // ---- GEMM2: [16x256] @ [256x128] + hmid + b2 -> out ----
    {
        const int c  = tid & 127;
        const int rg = tid >> 7;
        float acc[8];
        #pragma unroll
        for (int r = 0; r < 8; ++r) acc[r] = 0.f;
        for (int kk = 0; kk < 256; kk += 4) {
            float w0 = W2[(kk + 0) * 128 + c];
            float w1 = W2[(kk + 1) * 128 + c];
            float w2 = W2[(kk + 2) * 128 + c];
            float w3 = W2[(kk + 3) * 128 + c];
            #pragma unroll
            for (int r = 0; r < 8; ++r) {
                float4 a = *(const float4*)&tt[rg * 8 + r][kk];
                acc[r] = fmaf(a.x, w0, acc[r]);
                acc[r] = fmaf(a.y, w1, acc[r]);
                acc[r] = fmaf(a.z, w2, acc[r]);
                acc[r] = fmaf(a.w, w3, acc[r]);
            }
        }
        float bb = b2[c];
        #pragma unroll
        for (int r = 0; r < 8; ++r) {
            int row = row0 + rg * 8 + r;
            if (row < nrows)
                out[(size_t)row * 128 + c] = hm[rg * 8 + r][c] + acc[r] + bb;
        }
    }
}

// ---------------------------------------------------------------------------
extern "C" void kernel_launch(void* const* d_in, const int* in_sizes, int n_in,
                              void* d_out, int out_size, void* d_ws, size_t ws_size,
                              hipStream_t stream)
{
    const float* x    = (const float*)d_in[0];
    const int*   src  = (const int*)  d_in[1];
    const int*   dst  = (const int*)  d_in[2];
    const int*   gid  = (const int*)  d_in[3];
    const float* temb = (const float*)d_in[4];
    const float* Wsrc = (const float*)d_in[5];
    const float* bsrc = (const float*)d_in[6];
    const float* Wdst = (const float*)d_in[7];
    const float* bdst = (const float*)d_in[8];
    const float* attn = (const float*)d_in[9];
    const float* gbias= (const float*)d_in[10];
    const float* ln1g = (const float*)d_in[11];
    const float* ln1b = (const float*)d_in[12];
    const float* ln2g = (const float*)d_in[13];
    const float* ln2b = (const float*)d_in[14];
    const float* tW   = (const float*)d_in[15];
    const float* tb   = (const float*)d_in[16];
    const float* W1   = (const float*)d_in[17];
    const float* b1   = (const float*)d_in[18];
    const float* W2   = (const float*)d_in[19];
    const float* b2   = (const float*)d_in[20];

    const int N = in_sizes[0] / 128;
    const int E = in_sizes[1];
    const int B = in_sizes[4] / 128;
    float* out = (float*)d_out;

    // workspace layout
    char* ws = (char*)d_ws;
    size_t off = 0;
    float* fs   = (float*)(ws + off); off += (size_t)N * 128 * 4;   // 51.2 MB
    float* fd   = (float*)(ws + off); off += (size_t)N * 128 * 4;   // 51.2 MB (becomes hmid)
    int*   deg  = (int*)  (ws + off); off += (size_t)N * 4;
    int*   rs   = (int*)  (ws + off); off += (size_t)(N + 1) * 4;
    int*   rank = (int*)  (ws + off); off += (size_t)E * 4;         // 6.4 MB
    int*   eidx = (int*)  (ws + off); off += (size_t)E * 4;         // 6.4 MB
    float* tc   = (float*)(ws + off); off += (size_t)B * 128 * 4;

    hipMemsetAsync(deg, 0, (size_t)N * 4, stream);
    time_mlp<<<1, 256, 0, stream>>>(temb, tW, tb, tc, B);
    csr_rank<<<(E + 255) / 256, 256, 0, stream>>>(dst, deg, rank, E);
    csr_scan<<<1, 1024, 0, stream>>>(deg, rs, N, E);
    csr_fill<<<(E + 255) / 256, 256, 0, stream>>>(dst, rs, rank, eidx, E);
    ln1_dual_gemm<<<(N + RB - 1) / RB, 256, 0, stream>>>(
        x, ln1g, ln1b, Wsrc, bsrc, Wdst, bdst, fs, fd, N);
    gat_gather<<<(N + 3) / 4, 256, 0, stream>>>(
        fs, fd, x, eidx, rs, src, attn, gbias, gid, tc, N);
    combine_ffn<<<(N + RB - 1) / RB, 256, 0, stream>>>(
        fd, ln2g, ln2b, W1, b1, W2, b2, out, N);
}

// Round 3
// 625.834 us; speedup vs baseline: 3.2411x; 1.5260x over previous
//
#include <hip/hip_runtime.h>
#include <hip/hip_bf16.h>

// ResidualGATBlock: LN1 -> GATv2(4 heads) -> gelu -> +time_cond +x -> LN2 -> FFN -> residual
// N=100000, E=1600000, D=128, H=4, HD=32, B=8, TD=128. f32 I/O.
// Round 3: bf16 MFMA (16x16x32) for ln1 dual-GEMM and FFN; fs stored bf16.

#define RB 16
#define NEG_SLOPE 0.2f
#define LN_EPS 1e-5f

typedef __attribute__((ext_vector_type(8))) short short8v;   // 8 bf16 (4 VGPRs)
typedef __attribute__((ext_vector_type(4))) float floatx4;   // MFMA accum

__device__ __forceinline__ float gelu_erf(float v) {
    return 0.5f * v * (1.0f + erff(v * 0.70710678118654752f));
}
__device__ __forceinline__ unsigned short f2bf(float f) {    // RNE f32->bf16
    unsigned int u = __float_as_uint(f);
    u += 0x7fffu + ((u >> 16) & 1u);
    return (unsigned short)(u >> 16);
}
__device__ __forceinline__ float bf2f(unsigned short u) {
    return __uint_as_float(((unsigned int)u) << 16);
}

// ---------------------------------------------------------------------------
// pack W [K][C] f32 row-major -> bf16 B-fragments for mfma_f32_16x16x32_bf16.
// frag f = nt*(K/32)+kt ; lane l elem i = W[kt*32 + 8*(l>>4) + i][nt*16 + (l&15)]
// ---------------------------------------------------------------------------
__global__ __launch_bounds__(256) void pack_w(
    const float* __restrict__ W, unsigned short* __restrict__ P, int K, int C)
{
    int tid = blockIdx.x * 256 + threadIdx.x;
    int total = (K >> 5) * (C >> 4) * 64;
    if (tid >= total) return;
    int lane = tid & 63;
    int f = tid >> 6;
    int nkt = K >> 5;
    int nt = f / nkt, kt = f - nt * nkt;
    int col = nt * 16 + (lane & 15);
    int k0 = kt * 32 + 8 * (lane >> 4);
    short8v v;
    #pragma unroll
    for (int i = 0; i < 8; ++i)
        v[i] = (short)f2bf(W[(size_t)(k0 + i) * C + col]);
    *(short8v*)(P + (size_t)tid * 8) = v;
}

// ---------------------------------------------------------------------------
// Kernel 1: LN1 + dual MFMA GEMM. 16 rows/block, 4 waves.
//   fs (bf16) = LN(x)@Wsrc+bsrc ; fd (f32) = LN(x)@Wdst+bdst
// ---------------------------------------------------------------------------
__global__ __launch_bounds__(256) void ln1_dual_gemm(
    const float* __restrict__ x,
    const float* __restrict__ ln_g, const float* __restrict__ ln_b,
    const unsigned short* __restrict__ pWs, const float* __restrict__ bsrc,
    const unsigned short* __restrict__ pWd, const float* __restrict__ bdst,
    unsigned short* __restrict__ fs, float* __restrict__ fd, int nrows)
{
    __shared__ __align__(16) float hs[RB][132];          // +4 pad: bank-conflict-free
    __shared__ __align__(16) unsigned short pa[4 * 64 * 8]; // packed A frags (kt,lane,8)
    __shared__ float s_mu[RB], s_rs[RB];

    const int tid  = threadIdx.x;
    const int row0 = blockIdx.x * RB;
    const int lane = tid & 63;
    const int w    = tid >> 6;

    // ---- load 16 rows of x ----
    #pragma unroll
    for (int i = 0; i < 2; ++i) {
        int f   = tid + i * 256;
        int row = f >> 5;
        int c0  = (f & 31) * 4;
        float4 v = make_float4(0.f, 0.f, 0.f, 0.f);
        if (row0 + row < nrows) v = *(const float4*)(x + (size_t)(row0 + row) * 128 + c0);
        *(float4*)&hs[row][c0] = v;
    }
    __syncthreads();

    // ---- LN stats: wave per 4 rows ----
    {
        const int ln = lane;
        #pragma unroll
        for (int rr = 0; rr < 4; ++rr) {
            int row = w * 4 + rr;
            float v0 = hs[row][ln * 2], v1 = hs[row][ln * 2 + 1];
            float s = v0 + v1, sq = v0 * v0 + v1 * v1;
            #pragma unroll
            for (int m = 32; m; m >>= 1) { s += __shfl_xor(s, m); sq += __shfl_xor(sq, m); }
            if (ln == 0) {
                float mu  = s * (1.0f / 128.0f);
                float var = sq * (1.0f / 128.0f) - mu * mu;
                s_mu[row] = mu;
                s_rs[row] = rsqrtf(var + LN_EPS);
            }
        }
    }
    __syncthreads();

    // ---- normalize -> packed bf16 A-fragments ----
    {
        const int kt  = w;                    // 4 waves = 4 k-chunks
        const int row = lane & 15;
        const int k0  = kt * 32 + 8 * (lane >> 4);
        float mu = s_mu[row], rs = s_rs[row];
        float4 u  = *(float4*)&hs[row][k0];
        float4 v  = *(float4*)&hs[row][k0 + 4];
        float4 g0 = *(const float4*)&ln_g[k0];
        float4 g1 = *(const float4*)&ln_g[k0 + 4];
        float4 c0 = *(const float4*)&ln_b[k0];
        float4 c1 = *(const float4*)&ln_b[k0 + 4];
        short8v pv;
        pv[0] = (short)f2bf((u.x - mu) * rs * g0.x + c0.x);
        pv[1] = (short)f2bf((u.y - mu) * rs * g0.y + c0.y);
        pv[2] = (short)f2bf((u.z - mu) * rs * g0.z + c0.z);
        pv[3] = (short)f2bf((u.w - mu) * rs * g0.w + c0.w);
        pv[4] = (short)f2bf((v.x - mu) * rs * g1.x + c1.x);
        pv[5] = (short)f2bf((v.y - mu) * rs * g1.y + c1.y);
        pv[6] = (short)f2bf((v.z - mu) * rs * g1.z + c1.z);
        pv[7] = (short)f2bf((v.w - mu) * rs * g1.w + c1.w);
        *(short8v*)&pa[(kt * 64 + lane) * 8] = pv;
    }
    __syncthreads();

    // ---- dual MFMA GEMM: wave w -> col-tiles {2w, 2w+1} of both outputs ----
    short8v a[4];
    #pragma unroll
    for (int kt = 0; kt < 4; ++kt)
        a[kt] = *(const short8v*)&pa[(kt * 64 + lane) * 8];

    #pragma unroll
    for (int j = 0; j < 2; ++j) {
        const int nt = 2 * w + j;
        floatx4 aS = {0.f, 0.f, 0.f, 0.f};
        floatx4 aD = {0.f, 0.f, 0.f, 0.f};
        #pragma unroll
        for (int kt = 0; kt < 4; ++kt) {
            short8v bS = *(const short8v*)(pWs + (size_t)((nt * 4 + kt) * 64 + lane) * 8);
            aS = __builtin_amdgcn_mfma_f32_16x16x32_bf16(a[kt], bS, aS, 0, 0, 0);
            short8v bD = *(const short8v*)(pWd + (size_t)((nt * 4 + kt) * 64 + lane) * 8);
            aD = __builtin_amdgcn_mfma_f32_16x16x32_bf16(a[kt], bD, aD, 0, 0, 0);
        }
        const int col = nt * 16 + (lane & 15);
        const float bS0 = bsrc[col], bD0 = bdst[col];
        #pragma unroll
        for (int r = 0; r < 4; ++r) {
            int grow = row0 + 4 * (lane >> 4) + r;
            if (grow < nrows) {
                fs[(size_t)grow * 128 + col] = f2bf(aS[r] + bS0);
                fd[(size_t)grow * 128 + col] = aD[r] + bD0;
            }
        }
    }
}

// ---------------------------------------------------------------------------
// Kernel 2: time MLP
// ---------------------------------------------------------------------------
__global__ __launch_bounds__(256) void time_mlp(
    const float* __restrict__ temb, const float* __restrict__ tW,
    const float* __restrict__ tb, float* __restrict__ tc, int B)
{
    __shared__ float te[8 * 128];
    int tid = threadIdx.x;
    for (int i = tid; i < B * 128; i += 256) te[i] = temb[i];
    __syncthreads();
    int c = tid & 127, half = tid >> 7;
    for (int b = half * 4; b < half * 4 + 4; ++b) {
        if (b >= B) break;
        float acc = 0.f;
        for (int k = 0; k < 128; ++k) acc = fmaf(te[b * 128 + k], tW[k * 128 + c], acc);
        tc[b * 128 + c] = gelu_erf(acc + tb[c]);
    }
}

// ---------------------------------------------------------------------------
// CSR build: rank -> scan -> fill
// ---------------------------------------------------------------------------
__global__ __launch_bounds__(256) void csr_rank(
    const int* __restrict__ dst, int* __restrict__ deg, int* __restrict__ rank, int E)
{
    int e = blockIdx.x * 256 + threadIdx.x;
    if (e < E) rank[e] = atomicAdd(&deg[dst[e]], 1);
}

__global__ __launch_bounds__(1024) void csr_scan(
    const int* __restrict__ deg, int* __restrict__ rs, int N, int E)
{
    __shared__ int wsum[16];
    const int t = threadIdx.x;
    const int C = (N + 1023) >> 10;
    const int lo = t * C;
    const int hi = min(N, lo + C);
    int s = 0;
    for (int i = lo; i < hi; ++i) s += deg[i];
    const int lane = t & 63, w = t >> 6;
    int v = s;
    #pragma unroll
    for (int m = 1; m < 64; m <<= 1) { int u = __shfl_up(v, m); if (lane >= m) v += u; }
    if (lane == 63) wsum[w] = v;
    __syncthreads();
    if (t == 0) {
        int acc = 0;
        for (int i = 0; i < 16; ++i) { int u = wsum[i]; wsum[i] = acc; acc += u; }
    }
    __syncthreads();
    int acc = wsum[w] + (v - s);
    for (int i = lo; i < hi; ++i) { rs[i] = acc; acc += deg[i]; }
    if (t == 0) rs[N] = E;
}

__global__ __launch_bounds__(256) void csr_fill(
    const int* __restrict__ dst, const int* __restrict__ rs,
    const int* __restrict__ rank, int* __restrict__ eidx, int E)
{
    int e = blockIdx.x * 256 + threadIdx.x;
    if (e < E) eidx[rs[dst[e]] + rank[e]] = e;
}

// ---------------------------------------------------------------------------
// Kernel 3: fused GAT gather (one wave per node); fs is bf16 now.
// Writes hmid = gelu(rst+gat_bias) + time_cond[gid] + x in place over fd.
// ---------------------------------------------------------------------------
__global__ __launch_bounds__(256) void gat_gather(
    const unsigned short* __restrict__ fs, float* __restrict__ fd,
    const float* __restrict__ x,
    const int* __restrict__ eidx, const int* __restrict__ rs,
    const int* __restrict__ srcArr,
    const float* __restrict__ attn, const float* __restrict__ gat_bias,
    const int* __restrict__ gid, const float* __restrict__ tc, int N)
{
    const int lane = threadIdx.x & 63;
    const int wib  = threadIdx.x >> 6;
    const int n    = blockIdx.x * 4 + wib;
    if (n >= N) return;

    const int head = lane >> 4;
    const int d0   = lane * 2;
    const float a0 = attn[head * 32 + (lane & 15) * 2];
    const float a1 = attn[head * 32 + (lane & 15) * 2 + 1];

    const float2 vd = *(const float2*)(fd + (size_t)n * 128 + d0);
    const int lo = rs[n], hi = rs[n + 1];

    float den = 0.f, w0 = 0.f, w1 = 0.f;
    for (int i = lo; i < hi; ++i) {
        int e = eidx[i];
        int s = srcArr[e];
        ushort2 us = *(const ushort2*)(fs + (size_t)s * 128 + d0);
        float vsx = bf2f(us.x), vsy = bf2f(us.y);
        float e0 = vsx + vd.x; e0 = e0 > 0.f ? e0 : NEG_SLOPE * e0;
        float e1 = vsy + vd.y; e1 = e1 > 0.f ? e1 : NEG_SLOPE * e1;
        float p = e0 * a0 + e1 * a1;
        p += __shfl_xor(p, 8);
        p += __shfl_xor(p, 4);
        p += __shfl_xor(p, 2);
        p += __shfl_xor(p, 1);
        float exv = __expf(p);
        den += exv;
        w0 = fmaf(exv, vsx, w0);
        w1 = fmaf(exv, vsy, w1);
    }
    const float inv = den > 0.f ? 1.0f / den : 0.f;
    const float r0 = w0 * inv, r1 = w1 * inv;

    const int g = gid[n];
    const float2 xx = *(const float2*)(x  + (size_t)n * 128 + d0);
    const float2 t2 = *(const float2*)(tc + (size_t)g * 128 + d0);
    float h0 = gelu_erf(r0 + gat_bias[d0])     + t2.x + xx.x;
    float h1 = gelu_erf(r1 + gat_bias[d0 + 1]) + t2.y + xx.y;
    *(float2*)(fd + (size_t)n * 128 + d0) = make_float2(h0, h1);
}

// ---------------------------------------------------------------------------
// Kernel 4: LN2 + FFN via MFMA. 16 rows/block, 4 waves.
//   out = hmid + gelu(LN2(hmid)@W1 + b1)@W2 + b2
// ---------------------------------------------------------------------------
__global__ __launch_bounds__(256) void combine_ffn(
    const float* __restrict__ hmg,
    const float* __restrict__ ln_g, const float* __restrict__ ln_b,
    const unsigned short* __restrict__ pW1, const float* __restrict__ b1,
    const unsigned short* __restrict__ pW2, const float* __restrict__ b2,
    float* __restrict__ out, int nrows)
{
    __shared__ __align__(16) float hs[RB][132];              // hmid (residual + LN input)
    __shared__ __align__(16) unsigned short pa[4 * 64 * 8];  // LN2 out, packed A frags
    __shared__ __align__(16) unsigned short a2[RB * 264];    // gelu(GEMM1), row-major +8 pad
    __shared__ float s_mu[RB], s_rs[RB];

    const int tid  = threadIdx.x;
    const int row0 = blockIdx.x * RB;
    const int lane = tid & 63;
    const int w    = tid >> 6;

    // ---- load hmid tile ----
    #pragma unroll
    for (int i = 0; i < 2; ++i) {
        int f   = tid + i * 256;
        int row = f >> 5;
        int c0  = (f & 31) * 4;
        float4 v = make_float4(0.f, 0.f, 0.f, 0.f);
        if (row0 + row < nrows) v = *(const float4*)(hmg + (size_t)(row0 + row) * 128 + c0);
        *(float4*)&hs[row][c0] = v;
    }
    __syncthreads();

    // ---- LN2 stats ----
    {
        const int ln = lane;
        #pragma unroll
        for (int rr = 0; rr < 4; ++rr) {
            int row = w * 4 + rr;
            float v0 = hs[row][ln * 2], v1 = hs[row][ln * 2 + 1];
            float s = v0 + v1, sq = v0 * v0 + v1 * v1;
            #pragma unroll
            for (int m = 32; m; m >>= 1) { s += __shfl_xor(s, m); sq += __shfl_xor(sq, m); }
            if (ln == 0) {
                float mu  = s * (1.0f / 128.0f);
                float var = sq * (1.0f / 128.0f) - mu * mu;
                s_mu[row] = mu;
                s_rs[row] = rsqrtf(var + LN_EPS);
            }
        }
    }
    __syncthreads();

    // ---- normalize -> packed bf16 A frags ----
    {
        const int kt  = w;
        const int row = lane & 15;
        const int k0  = kt * 32 + 8 * (lane >> 4);
        float mu = s_mu[row], rs = s_rs[row];
        float4 u  = *(float4*)&hs[row][k0];
        float4 v  = *(float4*)&hs[row][k0 + 4];
        float4 g0 = *(const float4*)&ln_g[k0];
        float4 g1 = *(const float4*)&ln_g[k0 + 4];
        float4 c0 = *(const float4*)&ln_b[k0];
        float4 c1 = *(const float4*)&ln_b[k0 + 4];
        short8v pv;
        pv[0] = (short)f2bf((u.x - mu) * rs * g0.x + c0.x);
        pv[1] = (short)f2bf((u.y - mu) * rs * g0.y + c0.y);
        pv[2] = (short)f2bf((u.z - mu) * rs * g0.z + c0.z);
        pv[3] = (short)f2bf((u.w - mu) * rs * g0.w + c0.w);
        pv[4] = (short)f2bf((v.x - mu) * rs * g1.x + c1.x);
        pv[5] = (short)f2bf((v.y - mu) * rs * g1.y + c1.y);
        pv[6] = (short)f2bf((v.z - mu) * rs * g1.z + c1.z);
        pv[7] = (short)f2bf((v.w - mu) * rs * g1.w + c1.w);
        *(short8v*)&pa[(kt * 64 + lane) * 8] = pv;
    }
    __syncthreads();

    // ---- GEMM1 (16x256, K=128): wave w -> col-tiles {4w..4w+3}; gelu -> a2 ----
    {
        short8v a[4];
        #pragma unroll
        for (int kt = 0; kt < 4; ++kt)
            a[kt] = *(const short8v*)&pa[(kt * 64 + lane) * 8];

        #pragma unroll
        for (int jj = 0; jj < 4; ++jj) {
            const int nt = 4 * w + jj;
            floatx4 acc = {0.f, 0.f, 0.f, 0.f};
            #pragma unroll
            for (int kt = 0; kt < 4; ++kt) {
                short8v b = *(const short8v*)(pW1 + (size_t)((nt * 4 + kt) * 64 + lane) * 8);
                acc = __builtin_amdgcn_mfma_f32_16x16x32_bf16(a[kt], b, acc, 0, 0, 0);
            }
            const int col = nt * 16 + (lane & 15);
            const float bb = b1[col];
            #pragma unroll
            for (int r = 0; r < 4; ++r) {
                int rowD = 4 * (lane >> 4) + r;
                a2[rowD * 264 + col] = f2bf(gelu_erf(acc[r] + bb));
            }
        }
    }
    __syncthreads();

    // ---- GEMM2 (16x128, K=256): wave w -> col-tiles {2w, 2w+1} ----
    {
        floatx4 acc2[2] = {{0.f, 0.f, 0.f, 0.f}, {0.f, 0.f, 0.f, 0.f}};
        #pragma unroll
        for (int kt = 0; kt < 8; ++kt) {
            short8v af = *(const short8v*)&a2[(lane & 15) * 264 + kt * 32 + 8 * (lane >> 4)];
            #pragma unroll
            for (int j = 0; j < 2; ++j) {
                const int nt = 2 * w + j;
                short8v b = *(const short8v*)(pW2 + (size_t)((nt * 8 + kt) * 64 + lane) * 8);
                acc2[j] = __builtin_amdgcn_mfma_f32_16x16x32_bf16(af, b, acc2[j], 0, 0, 0);
            }
        }
        #pragma unroll
        for (int j = 0; j < 2; ++j) {
            const int col = (2 * w + j) * 16 + (lane & 15);
            const float bb = b2[col];
            #pragma unroll
            for (int r = 0; r < 4; ++r) {
                int rowD = 4 * (lane >> 4) + r;
                int grow = row0 + rowD;
                if (grow < nrows)
                    out[(size_t)grow * 128 + col] = hs[rowD][col] + acc2[j][r] + bb;
            }
        }
    }
}

// ---------------------------------------------------------------------------
extern "C" void kernel_launch(void* const* d_in, const int* in_sizes, int n_in,
                              void* d_out, int out_size, void* d_ws, size_t ws_size,
                              hipStream_t stream)
{
    const float* x    = (const float*)d_in[0];
    const int*   src  = (const int*)  d_in[1];
    const int*   dst  = (const int*)  d_in[2];
    const int*   gid  = (const int*)  d_in[3];
    const float* temb = (const float*)d_in[4];
    const float* Wsrc = (const float*)d_in[5];
    const float* bsrc = (const float*)d_in[6];
    const float* Wdst = (const float*)d_in[7];
    const float* bdst = (const float*)d_in[8];
    const float* attn = (const float*)d_in[9];
    const float* gbias= (const float*)d_in[10];
    const float* ln1g = (const float*)d_in[11];
    const float* ln1b = (const float*)d_in[12];
    const float* ln2g = (const float*)d_in[13];
    const float* ln2b = (const float*)d_in[14];
    const float* tW   = (const float*)d_in[15];
    const float* tb   = (const float*)d_in[16];
    const float* W1   = (const float*)d_in[17];
    const float* b1   = (const float*)d_in[18];
    const float* W2   = (const float*)d_in[19];
    const float* b2   = (const float*)d_in[20];

    const int N = in_sizes[0] / 128;
    const int E = in_sizes[1];
    const int B = in_sizes[4] / 128;
    float* out = (float*)d_out;

    // workspace layout (256B-aligned chunks)
    char* ws = (char*)d_ws;
    size_t off = 0;
    auto alloc = [&](size_t bytes) { void* p = ws + off; off += (bytes + 255) & ~(size_t)255; return p; };
    unsigned short* fs  = (unsigned short*)alloc((size_t)N * 128 * 2);  // bf16 feat_src
    float* fd           = (float*)         alloc((size_t)N * 128 * 4);  // f32 feat_dst -> hmid
    int*   deg          = (int*)           alloc((size_t)N * 4);
    int*   rsb          = (int*)           alloc((size_t)(N + 1) * 4);
    int*   rank         = (int*)           alloc((size_t)E * 4);
    int*   eidx         = (int*)           alloc((size_t)E * 4);
    float* tc           = (float*)         alloc((size_t)B * 128 * 4);
    unsigned short* pWs = (unsigned short*)alloc((size_t)128 * 128 * 2);
    unsigned short* pWd = (unsigned short*)alloc((size_t)128 * 128 * 2);
    unsigned short* pW1 = (unsigned short*)alloc((size_t)128 * 256 * 2);
    unsigned short* pW2 = (unsigned short*)alloc((size_t)256 * 128 * 2);

    hipMemsetAsync(deg, 0, (size_t)N * 4, stream);
    time_mlp<<<1, 256, 0, stream>>>(temb, tW, tb, tc, B);
    pack_w<<<(4 * 8 * 64 + 255) / 256, 256, 0, stream>>>(Wsrc, pWs, 128, 128);
    pack_w<<<(4 * 8 * 64 + 255) / 256, 256, 0, stream>>>(Wdst, pWd, 128, 128);
    pack_w<<<(4 * 16 * 64 + 255) / 256, 256, 0, stream>>>(W1, pW1, 128, 256);
    pack_w<<<(8 * 8 * 64 + 255) / 256, 256, 0, stream>>>(W2, pW2, 256, 128);
    csr_rank<<<(E + 255) / 256, 256, 0, stream>>>(dst, deg, rank, E);
    csr_scan<<<1, 1024, 0, stream>>>(deg, rsb, N, E);
    csr_fill<<<(E + 255) / 256, 256, 0, stream>>>(dst, rsb, rank, eidx, E);
    ln1_dual_gemm<<<(N + RB - 1) / RB, 256, 0, stream>>>(
        x, ln1g, ln1b, pWs, bsrc, pWd, bdst, fs, fd, N);
    gat_gather<<<(N + 3) / 4, 256, 0, stream>>>(
        fs, fd, x, eidx, rsb, src, attn, gbias, gid, tc, N);
    combine_ffn<<<(N + RB - 1) / RB, 256, 0, stream>>>(
        fd, ln2g, ln2b, pW1, b1, pW2, b2, out, N);
}

// Round 4
// 458.162 us; speedup vs baseline: 4.4272x; 1.3660x over previous
//
#include <hip/hip_runtime.h>
#include <hip/hip_bf16.h>

// ResidualGATBlock: LN1 -> GATv2(4 heads) -> gelu -> +time_cond +x -> LN2 -> FFN -> residual
// N=100000, E=1600000, D=128, H=4, HD=32, B=8, TD=128. f32 I/O.
// Round 4: gat_gather rebuilt — 2 edges/wave (half-wave x 4 dims), srcSorted
// direct (no eidx indirection), 2-deep software pipeline. MFMA GEMMs as r3.

#define RB 16
#define NEG_SLOPE 0.2f
#define LN_EPS 1e-5f

typedef __attribute__((ext_vector_type(8))) short short8v;   // 8 bf16 (4 VGPRs)
typedef __attribute__((ext_vector_type(4))) float floatx4;   // MFMA accum

__device__ __forceinline__ float gelu_erf(float v) {
    return 0.5f * v * (1.0f + erff(v * 0.70710678118654752f));
}
__device__ __forceinline__ unsigned short f2bf(float f) {    // RNE f32->bf16
    unsigned int u = __float_as_uint(f);
    u += 0x7fffu + ((u >> 16) & 1u);
    return (unsigned short)(u >> 16);
}
__device__ __forceinline__ float bf2f(unsigned short u) {
    return __uint_as_float(((unsigned int)u) << 16);
}

// ---------------------------------------------------------------------------
// pack W [K][C] f32 row-major -> bf16 B-fragments for mfma_f32_16x16x32_bf16.
// frag f = nt*(K/32)+kt ; lane l elem i = W[kt*32 + 8*(l>>4) + i][nt*16 + (l&15)]
// ---------------------------------------------------------------------------
__global__ __launch_bounds__(256) void pack_w(
    const float* __restrict__ W, unsigned short* __restrict__ P, int K, int C)
{
    int tid = blockIdx.x * 256 + threadIdx.x;
    int total = (K >> 5) * (C >> 4) * 64;
    if (tid >= total) return;
    int lane = tid & 63;
    int f = tid >> 6;
    int nkt = K >> 5;
    int nt = f / nkt, kt = f - nt * nkt;
    int col = nt * 16 + (lane & 15);
    int k0 = kt * 32 + 8 * (lane >> 4);
    short8v v;
    #pragma unroll
    for (int i = 0; i < 8; ++i)
        v[i] = (short)f2bf(W[(size_t)(k0 + i) * C + col]);
    *(short8v*)(P + (size_t)tid * 8) = v;
}

// ---------------------------------------------------------------------------
// Kernel 1: LN1 + dual MFMA GEMM. 16 rows/block, 4 waves.
//   fs (bf16) = LN(x)@Wsrc+bsrc ; fd (f32) = LN(x)@Wdst+bdst
// ---------------------------------------------------------------------------
__global__ __launch_bounds__(256) void ln1_dual_gemm(
    const float* __restrict__ x,
    const float* __restrict__ ln_g, const float* __restrict__ ln_b,
    const unsigned short* __restrict__ pWs, const float* __restrict__ bsrc,
    const unsigned short* __restrict__ pWd, const float* __restrict__ bdst,
    unsigned short* __restrict__ fs, float* __restrict__ fd, int nrows)
{
    __shared__ __align__(16) float hs[RB][132];
    __shared__ __align__(16) unsigned short pa[4 * 64 * 8];
    __shared__ float s_mu[RB], s_rs[RB];

    const int tid  = threadIdx.x;
    const int row0 = blockIdx.x * RB;
    const int lane = tid & 63;
    const int w    = tid >> 6;

    #pragma unroll
    for (int i = 0; i < 2; ++i) {
        int f   = tid + i * 256;
        int row = f >> 5;
        int c0  = (f & 31) * 4;
        float4 v = make_float4(0.f, 0.f, 0.f, 0.f);
        if (row0 + row < nrows) v = *(const float4*)(x + (size_t)(row0 + row) * 128 + c0);
        *(float4*)&hs[row][c0] = v;
    }
    __syncthreads();

    {
        const int ln = lane;
        #pragma unroll
        for (int rr = 0; rr < 4; ++rr) {
            int row = w * 4 + rr;
            float v0 = hs[row][ln * 2], v1 = hs[row][ln * 2 + 1];
            float s = v0 + v1, sq = v0 * v0 + v1 * v1;
            #pragma unroll
            for (int m = 32; m; m >>= 1) { s += __shfl_xor(s, m); sq += __shfl_xor(sq, m); }
            if (ln == 0) {
                float mu  = s * (1.0f / 128.0f);
                float var = sq * (1.0f / 128.0f) - mu * mu;
                s_mu[row] = mu;
                s_rs[row] = rsqrtf(var + LN_EPS);
            }
        }
    }
    __syncthreads();

    {
        const int kt  = w;
        const int row = lane & 15;
        const int k0  = kt * 32 + 8 * (lane >> 4);
        float mu = s_mu[row], rs = s_rs[row];
        float4 u  = *(float4*)&hs[row][k0];
        float4 v  = *(float4*)&hs[row][k0 + 4];
        float4 g0 = *(const float4*)&ln_g[k0];
        float4 g1 = *(const float4*)&ln_g[k0 + 4];
        float4 c0 = *(const float4*)&ln_b[k0];
        float4 c1 = *(const float4*)&ln_b[k0 + 4];
        short8v pv;
        pv[0] = (short)f2bf((u.x - mu) * rs * g0.x + c0.x);
        pv[1] = (short)f2bf((u.y - mu) * rs * g0.y + c0.y);
        pv[2] = (short)f2bf((u.z - mu) * rs * g0.z + c0.z);
        pv[3] = (short)f2bf((u.w - mu) * rs * g0.w + c0.w);
        pv[4] = (short)f2bf((v.x - mu) * rs * g1.x + c1.x);
        pv[5] = (short)f2bf((v.y - mu) * rs * g1.y + c1.y);
        pv[6] = (short)f2bf((v.z - mu) * rs * g1.z + c1.z);
        pv[7] = (short)f2bf((v.w - mu) * rs * g1.w + c1.w);
        *(short8v*)&pa[(kt * 64 + lane) * 8] = pv;
    }
    __syncthreads();

    short8v a[4];
    #pragma unroll
    for (int kt = 0; kt < 4; ++kt)
        a[kt] = *(const short8v*)&pa[(kt * 64 + lane) * 8];

    #pragma unroll
    for (int j = 0; j < 2; ++j) {
        const int nt = 2 * w + j;
        floatx4 aS = {0.f, 0.f, 0.f, 0.f};
        floatx4 aD = {0.f, 0.f, 0.f, 0.f};
        #pragma unroll
        for (int kt = 0; kt < 4; ++kt) {
            short8v bS = *(const short8v*)(pWs + (size_t)((nt * 4 + kt) * 64 + lane) * 8);
            aS = __builtin_amdgcn_mfma_f32_16x16x32_bf16(a[kt], bS, aS, 0, 0, 0);
            short8v bD = *(const short8v*)(pWd + (size_t)((nt * 4 + kt) * 64 + lane) * 8);
            aD = __builtin_amdgcn_mfma_f32_16x16x32_bf16(a[kt], bD, aD, 0, 0, 0);
        }
        const int col = nt * 16 + (lane & 15);
        const float bS0 = bsrc[col], bD0 = bdst[col];
        #pragma unroll
        for (int r = 0; r < 4; ++r) {
            int grow = row0 + 4 * (lane >> 4) + r;
            if (grow < nrows) {
                fs[(size_t)grow * 128 + col] = f2bf(aS[r] + bS0);
                fd[(size_t)grow * 128 + col] = aD[r] + bD0;
            }
        }
    }
}

// ---------------------------------------------------------------------------
// Kernel 2: time MLP
// ---------------------------------------------------------------------------
__global__ __launch_bounds__(256) void time_mlp(
    const float* __restrict__ temb, const float* __restrict__ tW,
    const float* __restrict__ tb, float* __restrict__ tc, int B)
{
    __shared__ float te[8 * 128];
    int tid = threadIdx.x;
    for (int i = tid; i < B * 128; i += 256) te[i] = temb[i];
    __syncthreads();
    int c = tid & 127, half = tid >> 7;
    for (int b = half * 4; b < half * 4 + 4; ++b) {
        if (b >= B) break;
        float acc = 0.f;
        for (int k = 0; k < 128; ++k) acc = fmaf(te[b * 128 + k], tW[k * 128 + c], acc);
        tc[b * 128 + c] = gelu_erf(acc + tb[c]);
    }
}

// ---------------------------------------------------------------------------
// CSR build: rank -> scan -> fill (fill emits srcSorted directly)
// ---------------------------------------------------------------------------
__global__ __launch_bounds__(256) void csr_rank(
    const int* __restrict__ dst, int* __restrict__ deg, int* __restrict__ rank, int E)
{
    int e = blockIdx.x * 256 + threadIdx.x;
    if (e < E) rank[e] = atomicAdd(&deg[dst[e]], 1);
}

__global__ __launch_bounds__(1024) void csr_scan(
    const int* __restrict__ deg, int* __restrict__ rs, int N, int E)
{
    __shared__ int wsum[16];
    const int t = threadIdx.x;
    const int C = (N + 1023) >> 10;
    const int lo = t * C;
    const int hi = min(N, lo + C);
    int s = 0;
    for (int i = lo; i < hi; ++i) s += deg[i];
    const int lane = t & 63, w = t >> 6;
    int v = s;
    #pragma unroll
    for (int m = 1; m < 64; m <<= 1) { int u = __shfl_up(v, m); if (lane >= m) v += u; }
    if (lane == 63) wsum[w] = v;
    __syncthreads();
    if (t == 0) {
        int acc = 0;
        for (int i = 0; i < 16; ++i) { int u = wsum[i]; wsum[i] = acc; acc += u; }
    }
    __syncthreads();
    int acc = wsum[w] + (v - s);
    for (int i = lo; i < hi; ++i) { rs[i] = acc; acc += deg[i]; }
    if (t == 0) rs[N] = E;
}

__global__ __launch_bounds__(256) void csr_fill(
    const int* __restrict__ dst, const int* __restrict__ src,
    const int* __restrict__ rs, const int* __restrict__ rank,
    int* __restrict__ srcSorted, int E)
{
    int e = blockIdx.x * 256 + threadIdx.x;
    if (e < E) srcSorted[rs[dst[e]] + rank[e]] = src[e];
}

// ---------------------------------------------------------------------------
// Kernel 3: fused GAT gather v2. One wave per node, 2 edges in flight via
// half-waves (32 lanes x 4 dims), plus 2-deep software pipeline (4 rows
// outstanding per wave). attn is flat over 128 dims -> per-lane float4.
// Score reduce: 3 shfl_xor within 8-lane head group. Halves merge at end.
// Writes hmid = gelu(rst+gat_bias) + time_cond[gid] + x in place over fd.
// ---------------------------------------------------------------------------
__global__ __launch_bounds__(256) void gat_gather(
    const unsigned short* __restrict__ fs, float* __restrict__ fd,
    const float* __restrict__ x,
    const int* __restrict__ srcSorted, const int* __restrict__ rs,
    const float* __restrict__ attn, const float* __restrict__ gat_bias,
    const int* __restrict__ gid, const float* __restrict__ tc, int N)
{
    const int lane = threadIdx.x & 63;
    const int wib  = threadIdx.x >> 6;
    const int n    = blockIdx.x * 4 + wib;
    if (n >= N) return;

    const int h   = lane >> 5;        // half-wave id: edge parity
    const int l32 = lane & 31;
    const int d0  = l32 * 4;          // this lane's 4 dims

    const float4 af = *(const float4*)(attn + d0);           // attn_flat[d] == attn[h][d-32h]
    const float4 vd = *(const float4*)(fd + (size_t)n * 128 + d0);

    const int lo = rs[n], hi = rs[n + 1];
    const int T  = (hi - lo + 1) >> 1;    // uniform trips across halves

    float den = 0.f, w0 = 0.f, w1 = 0.f, w2 = 0.f, w3 = 0.f;

    int i = lo + h;
    bool vA = (i < hi);
    int sA = vA ? srcSorted[i] : 0;
    ushort4 rA = *(const ushort4*)(fs + (size_t)sA * 128 + d0);

    for (int t = 0; t < T; ++t) {
        const int inext = i + 2;
        const bool vB = (inext < hi);
        const int sB = vB ? srcSorted[inext] : 0;
        ushort4 rB = *(const ushort4*)(fs + (size_t)sB * 128 + d0);  // prefetch

        float v0 = bf2f(rA.x), v1 = bf2f(rA.y), v2 = bf2f(rA.z), v3 = bf2f(rA.w);
        float e0 = v0 + vd.x; e0 = e0 > 0.f ? e0 : NEG_SLOPE * e0;
        float e1 = v1 + vd.y; e1 = e1 > 0.f ? e1 : NEG_SLOPE * e1;
        float e2 = v2 + vd.z; e2 = e2 > 0.f ? e2 : NEG_SLOPE * e2;
        float e3 = v3 + vd.w; e3 = e3 > 0.f ? e3 : NEG_SLOPE * e3;
        float p = e0 * af.x + e1 * af.y + e2 * af.z + e3 * af.w;
        p += __shfl_xor(p, 1);
        p += __shfl_xor(p, 2);
        p += __shfl_xor(p, 4);                 // head score across 8-lane group
        float exv = vA ? __expf(p) : 0.f;
        den += exv;
        w0 = fmaf(exv, v0, w0);
        w1 = fmaf(exv, v1, w1);
        w2 = fmaf(exv, v2, w2);
        w3 = fmaf(exv, v3, w3);

        vA = vB; rA = rB; i = inext;
    }

    // merge the two half-waves (paired lanes own the same dims)
    den += __shfl_xor(den, 32);
    w0  += __shfl_xor(w0, 32);
    w1  += __shfl_xor(w1, 32);
    w2  += __shfl_xor(w2, 32);
    w3  += __shfl_xor(w3, 32);

    if (h == 0) {
        const float inv = den > 0.f ? 1.0f / den : 0.f;
        const int g = gid[n];
        const float4 xx = *(const float4*)(x  + (size_t)n * 128 + d0);
        const float4 t4 = *(const float4*)(tc + (size_t)g * 128 + d0);
        const float4 gb = *(const float4*)(gat_bias + d0);
        float4 o;
        o.x = gelu_erf(w0 * inv + gb.x) + t4.x + xx.x;
        o.y = gelu_erf(w1 * inv + gb.y) + t4.y + xx.y;
        o.z = gelu_erf(w2 * inv + gb.z) + t4.z + xx.z;
        o.w = gelu_erf(w3 * inv + gb.w) + t4.w + xx.w;
        *(float4*)(fd + (size_t)n * 128 + d0) = o;
    }
}

// ---------------------------------------------------------------------------
// Kernel 4: LN2 + FFN via MFMA. 16 rows/block, 4 waves.
//   out = hmid + gelu(LN2(hmid)@W1 + b1)@W2 + b2
// ---------------------------------------------------------------------------
__global__ __launch_bounds__(256) void combine_ffn(
    const float* __restrict__ hmg,
    const float* __restrict__ ln_g, const float* __restrict__ ln_b,
    const unsigned short* __restrict__ pW1, const float* __restrict__ b1,
    const unsigned short* __restrict__ pW2, const float* __restrict__ b2,
    float* __restrict__ out, int nrows)
{
    __shared__ __align__(16) float hs[RB][132];
    __shared__ __align__(16) unsigned short pa[4 * 64 * 8];
    __shared__ __align__(16) unsigned short a2[RB * 264];
    __shared__ float s_mu[RB], s_rs[RB];

    const int tid  = threadIdx.x;
    const int row0 = blockIdx.x * RB;
    const int lane = tid & 63;
    const int w    = tid >> 6;

    #pragma unroll
    for (int i = 0; i < 2; ++i) {
        int f   = tid + i * 256;
        int row = f >> 5;
        int c0  = (f & 31) * 4;
        float4 v = make_float4(0.f, 0.f, 0.f, 0.f);
        if (row0 + row < nrows) v = *(const float4*)(hmg + (size_t)(row0 + row) * 128 + c0);
        *(float4*)&hs[row][c0] = v;
    }
    __syncthreads();

    {
        const int ln = lane;
        #pragma unroll
        for (int rr = 0; rr < 4; ++rr) {
            int row = w * 4 + rr;
            float v0 = hs[row][ln * 2], v1 = hs[row][ln * 2 + 1];
            float s = v0 + v1, sq = v0 * v0 + v1 * v1;
            #pragma unroll
            for (int m = 32; m; m >>= 1) { s += __shfl_xor(s, m); sq += __shfl_xor(sq, m); }
            if (ln == 0) {
                float mu  = s * (1.0f / 128.0f);
                float var = sq * (1.0f / 128.0f) - mu * mu;
                s_mu[row] = mu;
                s_rs[row] = rsqrtf(var + LN_EPS);
            }
        }
    }
    __syncthreads();

    {
        const int kt  = w;
        const int row = lane & 15;
        const int k0  = kt * 32 + 8 * (lane >> 4);
        float mu = s_mu[row], rs = s_rs[row];
        float4 u  = *(float4*)&hs[row][k0];
        float4 v  = *(float4*)&hs[row][k0 + 4];
        float4 g0 = *(const float4*)&ln_g[k0];
        float4 g1 = *(const float4*)&ln_g[k0 + 4];
        float4 c0 = *(const float4*)&ln_b[k0];
        float4 c1 = *(const float4*)&ln_b[k0 + 4];
        short8v pv;
        pv[0] = (short)f2bf((u.x - mu) * rs * g0.x + c0.x);
        pv[1] = (short)f2bf((u.y - mu) * rs * g0.y + c0.y);
        pv[2] = (short)f2bf((u.z - mu) * rs * g0.z + c0.z);
        pv[3] = (short)f2bf((u.w - mu) * rs * g0.w + c0.w);
        pv[4] = (short)f2bf((v.x - mu) * rs * g1.x + c1.x);
        pv[5] = (short)f2bf((v.y - mu) * rs * g1.y + c1.y);
        pv[6] = (short)f2bf((v.z - mu) * rs * g1.z + c1.z);
        pv[7] = (short)f2bf((v.w - mu) * rs * g1.w + c1.w);
        *(short8v*)&pa[(kt * 64 + lane) * 8] = pv;
    }
    __syncthreads();

    {
        short8v a[4];
        #pragma unroll
        for (int kt = 0; kt < 4; ++kt)
            a[kt] = *(const short8v*)&pa[(kt * 64 + lane) * 8];

        #pragma unroll
        for (int jj = 0; jj < 4; ++jj) {
            const int nt = 4 * w + jj;
            floatx4 acc = {0.f, 0.f, 0.f, 0.f};
            #pragma unroll
            for (int kt = 0; kt < 4; ++kt) {
                short8v b = *(const short8v*)(pW1 + (size_t)((nt * 4 + kt) * 64 + lane) * 8);
                acc = __builtin_amdgcn_mfma_f32_16x16x32_bf16(a[kt], b, acc, 0, 0, 0);
            }
            const int col = nt * 16 + (lane & 15);
            const float bb = b1[col];
            #pragma unroll
            for (int r = 0; r < 4; ++r) {
                int rowD = 4 * (lane >> 4) + r;
                a2[rowD * 264 + col] = f2bf(gelu_erf(acc[r] + bb));
            }
        }
    }
    __syncthreads();

    {
        floatx4 acc2[2] = {{0.f, 0.f, 0.f, 0.f}, {0.f, 0.f, 0.f, 0.f}};
        #pragma unroll
        for (int kt = 0; kt < 8; ++kt) {
            short8v af = *(const short8v*)&a2[(lane & 15) * 264 + kt * 32 + 8 * (lane >> 4)];
            #pragma unroll
            for (int j = 0; j < 2; ++j) {
                const int nt = 2 * w + j;
                short8v b = *(const short8v*)(pW2 + (size_t)((nt * 8 + kt) * 64 + lane) * 8);
                acc2[j] = __builtin_amdgcn_mfma_f32_16x16x32_bf16(af, b, acc2[j], 0, 0, 0);
            }
        }
        #pragma unroll
        for (int j = 0; j < 2; ++j) {
            const int col = (2 * w + j) * 16 + (lane & 15);
            const float bb = b2[col];
            #pragma unroll
            for (int r = 0; r < 4; ++r) {
                int rowD = 4 * (lane >> 4) + r;
                int grow = row0 + rowD;
                if (grow < nrows)
                    out[(size_t)grow * 128 + col] = hs[rowD][col] + acc2[j][r] + bb;
            }
        }
    }
}

// ---------------------------------------------------------------------------
extern "C" void kernel_launch(void* const* d_in, const int* in_sizes, int n_in,
                              void* d_out, int out_size, void* d_ws, size_t ws_size,
                              hipStream_t stream)
{
    const float* x    = (const float*)d_in[0];
    const int*   src  = (const int*)  d_in[1];
    const int*   dst  = (const int*)  d_in[2];
    const int*   gid  = (const int*)  d_in[3];
    const float* temb = (const float*)d_in[4];
    const float* Wsrc = (const float*)d_in[5];
    const float* bsrc = (const float*)d_in[6];
    const float* Wdst = (const float*)d_in[7];
    const float* bdst = (const float*)d_in[8];
    const float* attn = (const float*)d_in[9];
    const float* gbias= (const float*)d_in[10];
    const float* ln1g = (const float*)d_in[11];
    const float* ln1b = (const float*)d_in[12];
    const float* ln2g = (const float*)d_in[13];
    const float* ln2b = (const float*)d_in[14];
    const float* tW   = (const float*)d_in[15];
    const float* tb   = (const float*)d_in[16];
    const float* W1   = (const float*)d_in[17];
    const float* b1   = (const float*)d_in[18];
    const float* W2   = (const float*)d_in[19];
    const float* b2   = (const float*)d_in[20];

    const int N = in_sizes[0] / 128;
    const int E = in_sizes[1];
    const int B = in_sizes[4] / 128;
    float* out = (float*)d_out;

    char* ws = (char*)d_ws;
    size_t off = 0;
    auto alloc = [&](size_t bytes) { void* p = ws + off; off += (bytes + 255) & ~(size_t)255; return p; };
    unsigned short* fs  = (unsigned short*)alloc((size_t)N * 128 * 2);  // bf16 feat_src
    float* fd           = (float*)         alloc((size_t)N * 128 * 4);  // f32 feat_dst -> hmid
    int*   deg          = (int*)           alloc((size_t)N * 4);
    int*   rsb          = (int*)           alloc((size_t)(N + 1) * 4);
    int*   rank         = (int*)           alloc((size_t)E * 4);
    int*   srcSorted    = (int*)           alloc((size_t)E * 4);
    float* tc           = (float*)         alloc((size_t)B * 128 * 4);
    unsigned short* pWs = (unsigned short*)alloc((size_t)128 * 128 * 2);
    unsigned short* pWd = (unsigned short*)alloc((size_t)128 * 128 * 2);
    unsigned short* pW1 = (unsigned short*)alloc((size_t)128 * 256 * 2);
    unsigned short* pW2 = (unsigned short*)alloc((size_t)256 * 128 * 2);

    hipMemsetAsync(deg, 0, (size_t)N * 4, stream);
    time_mlp<<<1, 256, 0, stream>>>(temb, tW, tb, tc, B);
    pack_w<<<(4 * 8 * 64 + 255) / 256, 256, 0, stream>>>(Wsrc, pWs, 128, 128);
    pack_w<<<(4 * 8 * 64 + 255) / 256, 256, 0, stream>>>(Wdst, pWd, 128, 128);
    pack_w<<<(4 * 16 * 64 + 255) / 256, 256, 0, stream>>>(W1, pW1, 128, 256);
    pack_w<<<(8 * 8 * 64 + 255) / 256, 256, 0, stream>>>(W2, pW2, 256, 128);
    csr_rank<<<(E + 255) / 256, 256, 0, stream>>>(dst, deg, rank, E);
    csr_scan<<<1, 1024, 0, stream>>>(deg, rsb, N, E);
    csr_fill<<<(E + 255) / 256, 256, 0, stream>>>(dst, src, rsb, rank, srcSorted, E);
    ln1_dual_gemm<<<(N + RB - 1) / RB, 256, 0, stream>>>(
        x, ln1g, ln1b, pWs, bsrc, pWd, bdst, fs, fd, N);
    gat_gather<<<(N + 3) / 4, 256, 0, stream>>>(
        fs, fd, x, srcSorted, rsb, attn, gbias, gid, tc, N);
    combine_ffn<<<(N + RB - 1) / RB, 256, 0, stream>>>(
        fd, ln2g, ln2b, pW1, b1, pW2, b2, out, N);
}

// Round 5
// 307.724 us; speedup vs baseline: 6.5915x; 1.4889x over previous
//
#include <hip/hip_runtime.h>
#include <hip/hip_bf16.h>

// ResidualGATBlock: LN1 -> GATv2(4 heads) -> gelu -> +time_cond +x -> LN2 -> FFN -> residual
// N=100000, E=1600000, D=128, H=4, HD=32, B=8, TD=128. f32 I/O.
// Round 5: 3-phase parallel prefix scan replaces the single-block csr_scan
// (was 161 us at 0.16% occupancy). Rest unchanged from round 4.

#define RB 16
#define NEG_SLOPE 0.2f
#define LN_EPS 1e-5f

typedef __attribute__((ext_vector_type(8))) short short8v;   // 8 bf16 (4 VGPRs)
typedef __attribute__((ext_vector_type(4))) float floatx4;   // MFMA accum

__device__ __forceinline__ float gelu_erf(float v) {
    return 0.5f * v * (1.0f + erff(v * 0.70710678118654752f));
}
__device__ __forceinline__ unsigned short f2bf(float f) {    // RNE f32->bf16
    unsigned int u = __float_as_uint(f);
    u += 0x7fffu + ((u >> 16) & 1u);
    return (unsigned short)(u >> 16);
}
__device__ __forceinline__ float bf2f(unsigned short u) {
    return __uint_as_float(((unsigned int)u) << 16);
}

// ---------------------------------------------------------------------------
// pack W [K][C] f32 row-major -> bf16 B-fragments for mfma_f32_16x16x32_bf16.
// ---------------------------------------------------------------------------
__global__ __launch_bounds__(256) void pack_w(
    const float* __restrict__ W, unsigned short* __restrict__ P, int K, int C)
{
    int tid = blockIdx.x * 256 + threadIdx.x;
    int total = (K >> 5) * (C >> 4) * 64;
    if (tid >= total) return;
    int lane = tid & 63;
    int f = tid >> 6;
    int nkt = K >> 5;
    int nt = f / nkt, kt = f - nt * nkt;
    int col = nt * 16 + (lane & 15);
    int k0 = kt * 32 + 8 * (lane >> 4);
    short8v v;
    #pragma unroll
    for (int i = 0; i < 8; ++i)
        v[i] = (short)f2bf(W[(size_t)(k0 + i) * C + col]);
    *(short8v*)(P + (size_t)tid * 8) = v;
}

// ---------------------------------------------------------------------------
// Kernel 1: LN1 + dual MFMA GEMM. 16 rows/block, 4 waves.
// ---------------------------------------------------------------------------
__global__ __launch_bounds__(256) void ln1_dual_gemm(
    const float* __restrict__ x,
    const float* __restrict__ ln_g, const float* __restrict__ ln_b,
    const unsigned short* __restrict__ pWs, const float* __restrict__ bsrc,
    const unsigned short* __restrict__ pWd, const float* __restrict__ bdst,
    unsigned short* __restrict__ fs, float* __restrict__ fd, int nrows)
{
    __shared__ __align__(16) float hs[RB][132];
    __shared__ __align__(16) unsigned short pa[4 * 64 * 8];
    __shared__ float s_mu[RB], s_rs[RB];

    const int tid  = threadIdx.x;
    const int row0 = blockIdx.x * RB;
    const int lane = tid & 63;
    const int w    = tid >> 6;

    #pragma unroll
    for (int i = 0; i < 2; ++i) {
        int f   = tid + i * 256;
        int row = f >> 5;
        int c0  = (f & 31) * 4;
        float4 v = make_float4(0.f, 0.f, 0.f, 0.f);
        if (row0 + row < nrows) v = *(const float4*)(x + (size_t)(row0 + row) * 128 + c0);
        *(float4*)&hs[row][c0] = v;
    }
    __syncthreads();

    {
        const int ln = lane;
        #pragma unroll
        for (int rr = 0; rr < 4; ++rr) {
            int row = w * 4 + rr;
            float v0 = hs[row][ln * 2], v1 = hs[row][ln * 2 + 1];
            float s = v0 + v1, sq = v0 * v0 + v1 * v1;
            #pragma unroll
            for (int m = 32; m; m >>= 1) { s += __shfl_xor(s, m); sq += __shfl_xor(sq, m); }
            if (ln == 0) {
                float mu  = s * (1.0f / 128.0f);
                float var = sq * (1.0f / 128.0f) - mu * mu;
                s_mu[row] = mu;
                s_rs[row] = rsqrtf(var + LN_EPS);
            }
        }
    }
    __syncthreads();

    {
        const int kt  = w;
        const int row = lane & 15;
        const int k0  = kt * 32 + 8 * (lane >> 4);
        float mu = s_mu[row], rs = s_rs[row];
        float4 u  = *(float4*)&hs[row][k0];
        float4 v  = *(float4*)&hs[row][k0 + 4];
        float4 g0 = *(const float4*)&ln_g[k0];
        float4 g1 = *(const float4*)&ln_g[k0 + 4];
        float4 c0 = *(const float4*)&ln_b[k0];
        float4 c1 = *(const float4*)&ln_b[k0 + 4];
        short8v pv;
        pv[0] = (short)f2bf((u.x - mu) * rs * g0.x + c0.x);
        pv[1] = (short)f2bf((u.y - mu) * rs * g0.y + c0.y);
        pv[2] = (short)f2bf((u.z - mu) * rs * g0.z + c0.z);
        pv[3] = (short)f2bf((u.w - mu) * rs * g0.w + c0.w);
        pv[4] = (short)f2bf((v.x - mu) * rs * g1.x + c1.x);
        pv[5] = (short)f2bf((v.y - mu) * rs * g1.y + c1.y);
        pv[6] = (short)f2bf((v.z - mu) * rs * g1.z + c1.z);
        pv[7] = (short)f2bf((v.w - mu) * rs * g1.w + c1.w);
        *(short8v*)&pa[(kt * 64 + lane) * 8] = pv;
    }
    __syncthreads();

    short8v a[4];
    #pragma unroll
    for (int kt = 0; kt < 4; ++kt)
        a[kt] = *(const short8v*)&pa[(kt * 64 + lane) * 8];

    #pragma unroll
    for (int j = 0; j < 2; ++j) {
        const int nt = 2 * w + j;
        floatx4 aS = {0.f, 0.f, 0.f, 0.f};
        floatx4 aD = {0.f, 0.f, 0.f, 0.f};
        #pragma unroll
        for (int kt = 0; kt < 4; ++kt) {
            short8v bS = *(const short8v*)(pWs + (size_t)((nt * 4 + kt) * 64 + lane) * 8);
            aS = __builtin_amdgcn_mfma_f32_16x16x32_bf16(a[kt], bS, aS, 0, 0, 0);
            short8v bD = *(const short8v*)(pWd + (size_t)((nt * 4 + kt) * 64 + lane) * 8);
            aD = __builtin_amdgcn_mfma_f32_16x16x32_bf16(a[kt], bD, aD, 0, 0, 0);
        }
        const int col = nt * 16 + (lane & 15);
        const float bS0 = bsrc[col], bD0 = bdst[col];
        #pragma unroll
        for (int r = 0; r < 4; ++r) {
            int grow = row0 + 4 * (lane >> 4) + r;
            if (grow < nrows) {
                fs[(size_t)grow * 128 + col] = f2bf(aS[r] + bS0);
                fd[(size_t)grow * 128 + col] = aD[r] + bD0;
            }
        }
    }
}

// ---------------------------------------------------------------------------
// Kernel 2: time MLP
// ---------------------------------------------------------------------------
__global__ __launch_bounds__(256) void time_mlp(
    const float* __restrict__ temb, const float* __restrict__ tW,
    const float* __restrict__ tb, float* __restrict__ tc, int B)
{
    __shared__ float te[8 * 128];
    int tid = threadIdx.x;
    for (int i = tid; i < B * 128; i += 256) te[i] = temb[i];
    __syncthreads();
    int c = tid & 127, half = tid >> 7;
    for (int b = half * 4; b < half * 4 + 4; ++b) {
        if (b >= B) break;
        float acc = 0.f;
        for (int k = 0; k < 128; ++k) acc = fmaf(te[b * 128 + k], tW[k * 128 + c], acc);
        tc[b * 128 + c] = gelu_erf(acc + tb[c]);
    }
}

// ---------------------------------------------------------------------------
// CSR build: rank -> 3-phase scan -> fill (fill emits srcSorted directly)
// ---------------------------------------------------------------------------
__global__ __launch_bounds__(256) void csr_rank(
    const int* __restrict__ dst, int* __restrict__ deg, int* __restrict__ rank, int E)
{
    int e = blockIdx.x * 256 + threadIdx.x;
    if (e < E) rank[e] = atomicAdd(&deg[dst[e]], 1);
}

// Phase A: 256 threads/block, 1024 elements/block (4 per thread, int4).
// Writes block-local exclusive prefixes into rs and block totals into btot.
__global__ __launch_bounds__(256) void scan_blocks(
    const int* __restrict__ deg, int* __restrict__ rs, int* __restrict__ btot, int N)
{
    __shared__ int wtot[4];
    const int t    = threadIdx.x;
    const int idx  = blockIdx.x * 1024 + t * 4;
    int d0 = 0, d1 = 0, d2 = 0, d3 = 0;
    if (idx + 3 < N) {
        int4 v = *(const int4*)(deg + idx);
        d0 = v.x; d1 = v.y; d2 = v.z; d3 = v.w;
    } else {
        if (idx     < N) d0 = deg[idx];
        if (idx + 1 < N) d1 = deg[idx + 1];
        if (idx + 2 < N) d2 = deg[idx + 2];
        if (idx + 3 < N) d3 = deg[idx + 3];
    }
    const int ts = d0 + d1 + d2 + d3;
    const int lane = t & 63, w = t >> 6;
    int incl = ts;
    #pragma unroll
    for (int m = 1; m < 64; m <<= 1) { int u = __shfl_up(incl, m); if (lane >= m) incl += u; }
    if (lane == 63) wtot[w] = incl;
    __syncthreads();
    int woff = 0;
    #pragma unroll
    for (int i = 0; i < 4; ++i) woff += (i < w) ? wtot[i] : 0;
    const int p = woff + incl - ts;   // exclusive prefix of this thread's 4 elems
    if (idx + 3 < N) {
        int4 o;
        o.x = p; o.y = p + d0; o.z = p + d0 + d1; o.w = p + d0 + d1 + d2;
        *(int4*)(rs + idx) = o;
    } else {
        if (idx     < N) rs[idx]     = p;
        if (idx + 1 < N) rs[idx + 1] = p + d0;
        if (idx + 2 < N) rs[idx + 2] = p + d0 + d1;
        if (idx + 3 < N) rs[idx + 3] = p + d0 + d1 + d2;
    }
    if (t == 255) btot[blockIdx.x] = woff + incl;
}

// Phase B: one wave scans block totals in place (nb <= 128); writes rs[N]=E.
__global__ __launch_bounds__(64) void scan_tops(
    int* __restrict__ btot, int nb, int* __restrict__ rs, int N, int E)
{
    const int lane = threadIdx.x;
    int a0 = (2 * lane     < nb) ? btot[2 * lane]     : 0;
    int a1 = (2 * lane + 1 < nb) ? btot[2 * lane + 1] : 0;
    const int ts = a0 + a1;
    int incl = ts;
    #pragma unroll
    for (int m = 1; m < 64; m <<= 1) { int u = __shfl_up(incl, m); if (lane >= m) incl += u; }
    const int ex = incl - ts;
    if (2 * lane     < nb) btot[2 * lane]     = ex;
    if (2 * lane + 1 < nb) btot[2 * lane + 1] = ex + a0;
    if (lane == 0) rs[N] = E;
}

// Phase C: add block offsets.
__global__ __launch_bounds__(256) void scan_add(
    int* __restrict__ rs, const int* __restrict__ btot, int N)
{
    int i = blockIdx.x * 256 + threadIdx.x;
    if (i < N) rs[i] += btot[i >> 10];
}

__global__ __launch_bounds__(256) void csr_fill(
    const int* __restrict__ dst, const int* __restrict__ src,
    const int* __restrict__ rs, const int* __restrict__ rank,
    int* __restrict__ srcSorted, int E)
{
    int e = blockIdx.x * 256 + threadIdx.x;
    if (e < E) srcSorted[rs[dst[e]] + rank[e]] = src[e];
}

// ---------------------------------------------------------------------------
// Kernel 3: fused GAT gather v2 (2 edges/wave, 2-deep pipeline).
// ---------------------------------------------------------------------------
__global__ __launch_bounds__(256) void gat_gather(
    const unsigned short* __restrict__ fs, float* __restrict__ fd,
    const float* __restrict__ x,
    const int* __restrict__ srcSorted, const int* __restrict__ rs,
    const float* __restrict__ attn, const float* __restrict__ gat_bias,
    const int* __restrict__ gid, const float* __restrict__ tc, int N)
{
    const int lane = threadIdx.x & 63;
    const int wib  = threadIdx.x >> 6;
    const int n    = blockIdx.x * 4 + wib;
    if (n >= N) return;

    const int h   = lane >> 5;
    const int l32 = lane & 31;
    const int d0  = l32 * 4;

    const float4 af = *(const float4*)(attn + d0);
    const float4 vd = *(const float4*)(fd + (size_t)n * 128 + d0);

    const int lo = rs[n], hi = rs[n + 1];
    const int T  = (hi - lo + 1) >> 1;

    float den = 0.f, w0 = 0.f, w1 = 0.f, w2 = 0.f, w3 = 0.f;

    int i = lo + h;
    bool vA = (i < hi);
    int sA = vA ? srcSorted[i] : 0;
    ushort4 rA = *(const ushort4*)(fs + (size_t)sA * 128 + d0);

    for (int t = 0; t < T; ++t) {
        const int inext = i + 2;
        const bool vB = (inext < hi);
        const int sB = vB ? srcSorted[inext] : 0;
        ushort4 rB = *(const ushort4*)(fs + (size_t)sB * 128 + d0);

        float v0 = bf2f(rA.x), v1 = bf2f(rA.y), v2 = bf2f(rA.z), v3 = bf2f(rA.w);
        float e0 = v0 + vd.x; e0 = e0 > 0.f ? e0 : NEG_SLOPE * e0;
        float e1 = v1 + vd.y; e1 = e1 > 0.f ? e1 : NEG_SLOPE * e1;
        float e2 = v2 + vd.z; e2 = e2 > 0.f ? e2 : NEG_SLOPE * e2;
        float e3 = v3 + vd.w; e3 = e3 > 0.f ? e3 : NEG_SLOPE * e3;
        float p = e0 * af.x + e1 * af.y + e2 * af.z + e3 * af.w;
        p += __shfl_xor(p, 1);
        p += __shfl_xor(p, 2);
        p += __shfl_xor(p, 4);
        float exv = vA ? __expf(p) : 0.f;
        den += exv;
        w0 = fmaf(exv, v0, w0);
        w1 = fmaf(exv, v1, w1);
        w2 = fmaf(exv, v2, w2);
        w3 = fmaf(exv, v3, w3);

        vA = vB; rA = rB; i = inext;
    }

    den += __shfl_xor(den, 32);
    w0  += __shfl_xor(w0, 32);
    w1  += __shfl_xor(w1, 32);
    w2  += __shfl_xor(w2, 32);
    w3  += __shfl_xor(w3, 32);

    if (h == 0) {
        const float inv = den > 0.f ? 1.0f / den : 0.f;
        const int g = gid[n];
        const float4 xx = *(const float4*)(x  + (size_t)n * 128 + d0);
        const float4 t4 = *(const float4*)(tc + (size_t)g * 128 + d0);
        const float4 gb = *(const float4*)(gat_bias + d0);
        float4 o;
        o.x = gelu_erf(w0 * inv + gb.x) + t4.x + xx.x;
        o.y = gelu_erf(w1 * inv + gb.y) + t4.y + xx.y;
        o.z = gelu_erf(w2 * inv + gb.z) + t4.z + xx.z;
        o.w = gelu_erf(w3 * inv + gb.w) + t4.w + xx.w;
        *(float4*)(fd + (size_t)n * 128 + d0) = o;
    }
}

// ---------------------------------------------------------------------------
// Kernel 4: LN2 + FFN via MFMA. 16 rows/block, 4 waves.
// ---------------------------------------------------------------------------
__global__ __launch_bounds__(256) void combine_ffn(
    const float* __restrict__ hmg,
    const float* __restrict__ ln_g, const float* __restrict__ ln_b,
    const unsigned short* __restrict__ pW1, const float* __restrict__ b1,
    const unsigned short* __restrict__ pW2, const float* __restrict__ b2,
    float* __restrict__ out, int nrows)
{
    __shared__ __align__(16) float hs[RB][132];
    __shared__ __align__(16) unsigned short pa[4 * 64 * 8];
    __shared__ __align__(16) unsigned short a2[RB * 264];
    __shared__ float s_mu[RB], s_rs[RB];

    const int tid  = threadIdx.x;
    const int row0 = blockIdx.x * RB;
    const int lane = tid & 63;
    const int w    = tid >> 6;

    #pragma unroll
    for (int i = 0; i < 2; ++i) {
        int f   = tid + i * 256;
        int row = f >> 5;
        int c0  = (f & 31) * 4;
        float4 v = make_float4(0.f, 0.f, 0.f, 0.f);
        if (row0 + row < nrows) v = *(const float4*)(hmg + (size_t)(row0 + row) * 128 + c0);
        *(float4*)&hs[row][c0] = v;
    }
    __syncthreads();

    {
        const int ln = lane;
        #pragma unroll
        for (int rr = 0; rr < 4; ++rr) {
            int row = w * 4 + rr;
            float v0 = hs[row][ln * 2], v1 = hs[row][ln * 2 + 1];
            float s = v0 + v1, sq = v0 * v0 + v1 * v1;
            #pragma unroll
            for (int m = 32; m; m >>= 1) { s += __shfl_xor(s, m); sq += __shfl_xor(sq, m); }
            if (ln == 0) {
                float mu  = s * (1.0f / 128.0f);
                float var = sq * (1.0f / 128.0f) - mu * mu;
                s_mu[row] = mu;
                s_rs[row] = rsqrtf(var + LN_EPS);
            }
        }
    }
    __syncthreads();

    {
        const int kt  = w;
        const int row = lane & 15;
        const int k0  = kt * 32 + 8 * (lane >> 4);
        float mu = s_mu[row], rs = s_rs[row];
        float4 u  = *(float4*)&hs[row][k0];
        float4 v  = *(float4*)&hs[row][k0 + 4];
        float4 g0 = *(const float4*)&ln_g[k0];
        float4 g1 = *(const float4*)&ln_g[k0 + 4];
        float4 c0 = *(const float4*)&ln_b[k0];
        float4 c1 = *(const float4*)&ln_b[k0 + 4];
        short8v pv;
        pv[0] = (short)f2bf((u.x - mu) * rs * g0.x + c0.x);
        pv[1] = (short)f2bf((u.y - mu) * rs * g0.y + c0.y);
        pv[2] = (short)f2bf((u.z - mu) * rs * g0.z + c0.z);
        pv[3] = (short)f2bf((u.w - mu) * rs * g0.w + c0.w);
        pv[4] = (short)f2bf((v.x - mu) * rs * g1.x + c1.x);
        pv[5] = (short)f2bf((v.y - mu) * rs * g1.y + c1.y);
        pv[6] = (short)f2bf((v.z - mu) * rs * g1.z + c1.z);
        pv[7] = (short)f2bf((v.w - mu) * rs * g1.w + c1.w);
        *(short8v*)&pa[(kt * 64 + lane) * 8] = pv;
    }
    __syncthreads();

    {
        short8v a[4];
        #pragma unroll
        for (int kt = 0; kt < 4; ++kt)
            a[kt] = *(const short8v*)&pa[(kt * 64 + lane) * 8];

        #pragma unroll
        for (int jj = 0; jj < 4; ++jj) {
            const int nt = 4 * w + jj;
            floatx4 acc = {0.f, 0.f, 0.f, 0.f};
            #pragma unroll
            for (int kt = 0; kt < 4; ++kt) {
                short8v b = *(const short8v*)(pW1 + (size_t)((nt * 4 + kt) * 64 + lane) * 8);
                acc = __builtin_amdgcn_mfma_f32_16x16x32_bf16(a[kt], b, acc, 0, 0, 0);
            }
            const int col = nt * 16 + (lane & 15);
            const float bb = b1[col];
            #pragma unroll
            for (int r = 0; r < 4; ++r) {
                int rowD = 4 * (lane >> 4) + r;
                a2[rowD * 264 + col] = f2bf(gelu_erf(acc[r] + bb));
            }
        }
    }
    __syncthreads();

    {
        floatx4 acc2[2] = {{0.f, 0.f, 0.f, 0.f}, {0.f, 0.f, 0.f, 0.f}};
        #pragma unroll
        for (int kt = 0; kt < 8; ++kt) {
            short8v af = *(const short8v*)&a2[(lane & 15) * 264 + kt * 32 + 8 * (lane >> 4)];
            #pragma unroll
            for (int j = 0; j < 2; ++j) {
                const int nt = 2 * w + j;
                short8v b = *(const short8v*)(pW2 + (size_t)((nt * 8 + kt) * 64 + lane) * 8);
                acc2[j] = __builtin_amdgcn_mfma_f32_16x16x32_bf16(af, b, acc2[j], 0, 0, 0);
            }
        }
        #pragma unroll
        for (int j = 0; j < 2; ++j) {
            const int col = (2 * w + j) * 16 + (lane & 15);
            const float bb = b2[col];
            #pragma unroll
            for (int r = 0; r < 4; ++r) {
                int rowD = 4 * (lane >> 4) + r;
                int grow = row0 + rowD;
                if (grow < nrows)
                    out[(size_t)grow * 128 + col] = hs[rowD][col] + acc2[j][r] + bb;
            }
        }
    }
}

// ---------------------------------------------------------------------------
extern "C" void kernel_launch(void* const* d_in, const int* in_sizes, int n_in,
                              void* d_out, int out_size, void* d_ws, size_t ws_size,
                              hipStream_t stream)
{
    const float* x    = (const float*)d_in[0];
    const int*   src  = (const int*)  d_in[1];
    const int*   dst  = (const int*)  d_in[2];
    const int*   gid  = (const int*)  d_in[3];
    const float* temb = (const float*)d_in[4];
    const float* Wsrc = (const float*)d_in[5];
    const float* bsrc = (const float*)d_in[6];
    const float* Wdst = (const float*)d_in[7];
    const float* bdst = (const float*)d_in[8];
    const float* attn = (const float*)d_in[9];
    const float* gbias= (const float*)d_in[10];
    const float* ln1g = (const float*)d_in[11];
    const float* ln1b = (const float*)d_in[12];
    const float* ln2g = (const float*)d_in[13];
    const float* ln2b = (const float*)d_in[14];
    const float* tW   = (const float*)d_in[15];
    const float* tb   = (const float*)d_in[16];
    const float* W1   = (const float*)d_in[17];
    const float* b1   = (const float*)d_in[18];
    const float* W2   = (const float*)d_in[19];
    const float* b2   = (const float*)d_in[20];

    const int N = in_sizes[0] / 128;
    const int E = in_sizes[1];
    const int B = in_sizes[4] / 128;
    float* out = (float*)d_out;

    char* ws = (char*)d_ws;
    size_t off = 0;
    auto alloc = [&](size_t bytes) { void* p = ws + off; off += (bytes + 255) & ~(size_t)255; return p; };
    unsigned short* fs  = (unsigned short*)alloc((size_t)N * 128 * 2);  // bf16 feat_src
    float* fd           = (float*)         alloc((size_t)N * 128 * 4);  // f32 feat_dst -> hmid
    int*   deg          = (int*)           alloc((size_t)N * 4);
    int*   rsb          = (int*)           alloc((size_t)(N + 1) * 4);
    int*   rank         = (int*)           alloc((size_t)E * 4);
    int*   srcSorted    = (int*)           alloc((size_t)E * 4);
    float* tc           = (float*)         alloc((size_t)B * 128 * 4);
    int*   btot         = (int*)           alloc((size_t)1024 * 4);
    unsigned short* pWs = (unsigned short*)alloc((size_t)128 * 128 * 2);
    unsigned short* pWd = (unsigned short*)alloc((size_t)128 * 128 * 2);
    unsigned short* pW1 = (unsigned short*)alloc((size_t)128 * 256 * 2);
    unsigned short* pW2 = (unsigned short*)alloc((size_t)256 * 128 * 2);

    const int nbScan = (N + 1023) >> 10;   // 98 for N=100000 (<=128 required)

    hipMemsetAsync(deg, 0, (size_t)N * 4, stream);
    time_mlp<<<1, 256, 0, stream>>>(temb, tW, tb, tc, B);
    pack_w<<<(4 * 8 * 64 + 255) / 256, 256, 0, stream>>>(Wsrc, pWs, 128, 128);
    pack_w<<<(4 * 8 * 64 + 255) / 256, 256, 0, stream>>>(Wdst, pWd, 128, 128);
    pack_w<<<(4 * 16 * 64 + 255) / 256, 256, 0, stream>>>(W1, pW1, 128, 256);
    pack_w<<<(8 * 8 * 64 + 255) / 256, 256, 0, stream>>>(W2, pW2, 256, 128);
    csr_rank<<<(E + 255) / 256, 256, 0, stream>>>(dst, deg, rank, E);
    scan_blocks<<<nbScan, 256, 0, stream>>>(deg, rsb, btot, N);
    scan_tops<<<1, 64, 0, stream>>>(btot, nbScan, rsb, N, E);
    scan_add<<<(N + 255) / 256, 256, 0, stream>>>(rsb, btot, N);
    csr_fill<<<(E + 255) / 256, 256, 0, stream>>>(dst, src, rsb, rank, srcSorted, E);
    ln1_dual_gemm<<<(N + RB - 1) / RB, 256, 0, stream>>>(
        x, ln1g, ln1b, pWs, bsrc, pWd, bdst, fs, fd, N);
    gat_gather<<<(N + 3) / 4, 256, 0, stream>>>(
        fs, fd, x, srcSorted, rsb, attn, gbias, gid, tc, N);
    combine_ffn<<<(N + RB - 1) / RB, 256, 0, stream>>>(
        fd, ln2g, ln2b, pW1, b1, pW2, b2, out, N);
}